// Round 4
// baseline (267.822 us; speedup 1.0000x reference)
//
#include <hip/hip_runtime.h>
#include <hip/hip_bf16.h>

#define SLOPE 0.1f
typedef unsigned short u16;
typedef unsigned int u32;
typedef __attribute__((ext_vector_type(8))) short short8;
typedef __attribute__((ext_vector_type(4))) float floatx4;

__device__ __forceinline__ float lrelu(float x) { return x > 0.0f ? x : SLOPE * x; }

// round-nearest split: x ~= hi + lo (bf16 each), rel err ~2^-17
__device__ __forceinline__ void split_rn(float x, u16* h, u16* l) {
    union { __hip_bfloat16 b; u16 u; } c1, c2;
    c1.b = __float2bfloat16(x);
    float hf = __bfloat162float(c1.b);
    c2.b = __float2bfloat16(x - hf);
    *h = c1.u; *l = c2.u;
}

// truncation split (cheap, ~2^-16 rel): hi = trunc-bf16(x), lo = trunc-bf16(x-hi)
__device__ __forceinline__ void split_t(float x, u16& h, u16& l) {
    u32 ub = __float_as_uint(x);
    float hf = __uint_as_float(ub & 0xFFFF0000u);
    h = (u16)(ub >> 16);
    l = (u16)(__float_as_uint(x - hf) >> 16);
}

__device__ __forceinline__ short8 load_frag(const u16* p) {
    union { uint4 q; short8 s; } cv;
    cv.q = *(const uint4*)p;
    return cv.s;
}

__device__ __forceinline__ floatx4 mfma16(short8 a, short8 b, floatx4 c) {
    return __builtin_amdgcn_mfma_f32_16x16x32_bf16(a, b, c, 0, 0, 0);
}

// ---------------------------------------------------------------------------
// P0: one-shot preprocessing (unchanged).
// ---------------------------------------------------------------------------
__global__ __launch_bounds__(256) void p0_prep(
    const float* __restrict__ x,
    const float* __restrict__ cw0, const float* __restrict__ cw1,
    const float* __restrict__ cw2, const float* __restrict__ cw3,
    const float* __restrict__ mw0, const float* __restrict__ mw1,
    const float* __restrict__ mw2, const float* __restrict__ mw3,
    const float* __restrict__ lw0, const float* __restrict__ lw1,
    u16* __restrict__ xh, u16* __restrict__ xl,
    u16* __restrict__ wch, u16* __restrict__ wcl,
    u16* __restrict__ b2h, u16* __restrict__ b2l,
    u16* __restrict__ w3h, u16* __restrict__ w3l,
    float* __restrict__ lw0t, float* __restrict__ lw1t)
{
    int idx = blockIdx.x * 256 + threadIdx.x;
    if (idx < 1048576) { split_rn(x[idx], &xh[idx], &xl[idx]); return; }
    idx -= 1048576;
    if (idx < 524288) {
        const int slot = idx >> 15, c = (idx >> 9) & 63, e = idx & 511;
        int branch, base;
        if (slot == 0)      { branch = 0; base = 0; }
        else if (slot < 4)  { branch = 1; base = 1; }
        else if (slot < 9)  { branch = 2; base = 4; }
        else                { branch = 3; base = 9; }
        const int dk = slot - base, ksz = 2 * branch + 1;
        const float* cw = branch == 0 ? cw0 : branch == 1 ? cw1 : branch == 2 ? cw2 : cw3;
        split_rn(cw[(c * ksz + dk) * 512 + e], &wch[idx], &wcl[idx]);
        return;
    }
    idx -= 524288;
    if (idx < 32768) {
        const int n = idx >> 8, k = idx & 255;
        split_rn(mw0[(n & 63) * 512 + (n >> 6) * 256 + k], &b2h[idx], &b2l[idx]);
        return;
    }
    idx -= 32768;
    if (idx < 12288) {
        const int l = idx >> 12, n = (idx >> 6) & 63, k = idx & 63;
        const float* mw = l == 0 ? mw1 : l == 1 ? mw2 : mw3;
        split_rn(mw[n * 64 + k], &w3h[idx], &w3l[idx]);
        return;
    }
    idx -= 12288;
    if (idx < 4096) { const int k = idx >> 6, n = idx & 63; lw0t[idx] = lw0[n * 64 + k]; return; }
    idx -= 4096;
    if (idx < 16384) { const int k = idx >> 8, n = idx & 255; lw1t[idx] = lw1[n * 64 + k]; return; }
}

// ---------------------------------------------------------------------------
// K1: per-(slot) conv-tap GEMM via MFMA, no LDS (unchanged from R3).
// ---------------------------------------------------------------------------
__global__ __launch_bounds__(256) void k1_conv(
    const u16* __restrict__ xh, const u16* __restrict__ xl,
    const u16* __restrict__ wch, const u16* __restrict__ wcl,
    float* __restrict__ f_part)
{
    const int t = threadIdx.x, lane = t & 63, w = t >> 6;
    const int slot = blockIdx.x >> 5;
    const int m0 = (blockIdx.x & 31) * 64 + w * 16;
    int branch, base;
    if (slot == 0)      { branch = 0; base = 0; }
    else if (slot < 4)  { branch = 1; base = 1; }
    else if (slot < 9)  { branch = 2; base = 4; }
    else                { branch = 3; base = 9; }
    const int s = (slot - base) - branch;
    const int l15 = lane & 15, quad = lane >> 4;

    const u16* wbh = wch + slot * 32768;
    const u16* wbl = wcl + slot * 32768;

    floatx4 acc[4];
    #pragma unroll
    for (int j = 0; j < 4; ++j) acc[j] = (floatx4)0.0f;

    const int gbase = m0 + s * 16;
    const bool ok = (gbase >= 0) && (gbase < 2048);
    const int rowg = gbase + l15;

    const short8 zfrag = {0, 0, 0, 0, 0, 0, 0, 0};
    #pragma unroll 4
    for (int k0 = 0; k0 < 512; k0 += 32) {
        short8 ah, al;
        if (ok) {
            const int off = rowg * 512 + k0 + quad * 8;
            ah = load_frag(xh + off);
            al = load_frag(xl + off);
        } else { ah = zfrag; al = zfrag; }
        #pragma unroll
        for (int nt = 0; nt < 4; ++nt) {
            const int boff = (nt * 16 + l15) * 512 + k0 + quad * 8;
            const short8 bh = load_frag(wbh + boff);
            const short8 bl = load_frag(wbl + boff);
            acc[nt] = mfma16(ah, bh, acc[nt]);
            acc[nt] = mfma16(ah, bl, acc[nt]);
            acc[nt] = mfma16(al, bh, acc[nt]);
        }
    }

    float* fp = f_part + slot * 131072;
    #pragma unroll
    for (int nt = 0; nt < 4; ++nt)
        #pragma unroll
        for (int r = 0; r < 4; ++r)
            fp[(m0 + quad * 4 + r) * 64 + nt * 16 + l15] = acc[nt][r];
}

// ---------------------------------------------------------------------------
// K1b: tap-sum + conv bias + lrelu -> F (2048x256) split to bf16 hi/lo.
// ---------------------------------------------------------------------------
__global__ __launch_bounds__(256) void k1b_act(
    const float* __restrict__ f_part,
    const float* __restrict__ cb0, const float* __restrict__ cb1,
    const float* __restrict__ cb2, const float* __restrict__ cb3,
    u16* __restrict__ Fh, u16* __restrict__ Fl)
{
    const int idx = blockIdx.x * 256 + threadIdx.x;   // 131072
    const int r = idx >> 6, m4 = (idx & 63) * 4;
    const int branch = m4 >> 6, c = m4 & 63;
    int base, ksz; const float* cb;
    if (branch == 0)      { base = 0; ksz = 1; cb = cb0; }
    else if (branch == 1) { base = 1; ksz = 3; cb = cb1; }
    else if (branch == 2) { base = 4; ksz = 5; cb = cb2; }
    else                  { base = 9; ksz = 7; cb = cb3; }
    float4 sum = *(const float4*)(cb + c);
    const float* fp = f_part + base * 131072 + r * 64 + c;
    for (int d = 0; d < ksz; ++d) {
        const float4 p = *(const float4*)(fp + d * 131072);
        sum.x += p.x; sum.y += p.y; sum.z += p.z; sum.w += p.w;
    }
    float v4[4] = {lrelu(sum.x), lrelu(sum.y), lrelu(sum.z), lrelu(sum.w)};
    u16 h4[4], l4[4];
    #pragma unroll
    for (int i = 0; i < 4; ++i) split_rn(v4[i], &h4[i], &l4[i]);
    *(ushort4*)(Fh + r * 256 + m4) = make_ushort4(h4[0], h4[1], h4[2], h4[3]);
    *(ushort4*)(Fl + r * 256 + m4) = make_ushort4(l4[0], l4[1], l4[2], l4[3]);
}

// ---------------------------------------------------------------------------
// K2: [u|v] = F @ B2^T via MFMA, no LDS (unchanged from R3).
// ---------------------------------------------------------------------------
__global__ __launch_bounds__(64) void k2_uv(
    const u16* __restrict__ Fh, const u16* __restrict__ Fl,
    const u16* __restrict__ b2h, const u16* __restrict__ b2l,
    const float* __restrict__ mb0,
    float* __restrict__ u, float* __restrict__ v)
{
    const int lane = threadIdx.x & 63;
    const int m0 = blockIdx.x * 16;
    const int nhalf = blockIdx.y;
    const int l15 = lane & 15, quad = lane >> 4;

    floatx4 acc[4];
    #pragma unroll
    for (int j = 0; j < 4; ++j) acc[j] = (floatx4)0.0f;

    #pragma unroll 4
    for (int k0 = 0; k0 < 256; k0 += 32) {
        const int off = (m0 + l15) * 256 + k0 + quad * 8;
        const short8 ah = load_frag(Fh + off);
        const short8 al = load_frag(Fl + off);
        #pragma unroll
        for (int nt = 0; nt < 4; ++nt) {
            const int boff = (nhalf * 64 + nt * 16 + l15) * 256 + k0 + quad * 8;
            const short8 bh = load_frag(b2h + boff);
            const short8 bl = load_frag(b2l + boff);
            acc[nt] = mfma16(ah, bh, acc[nt]);
            acc[nt] = mfma16(ah, bl, acc[nt]);
            acc[nt] = mfma16(al, bh, acc[nt]);
        }
    }

    #pragma unroll
    for (int nt = 0; nt < 4; ++nt) {
        const int c = nt * 16 + l15;
        #pragma unroll
        for (int r = 0; r < 4; ++r) {
            const int row = m0 + quad * 4 + r;
            const float val = acc[nt][r];
            if (nhalf == 0) u[row * 64 + c] = val + mb0[c];
            else            v[row * 64 + c] = val;
        }
    }
}

// ---------------------------------------------------------------------------
// K3: per (jb, i-half): 64 i's, H in LDS bf16 hi/lo, wave-private 16-i strips,
// zero barriers across the 3 MFMA layers.  Layer-3 output reduced over i via
// shuffle butterflies (no LDS writeback).  Partial S -> global Spart.
// grid: 4096 blocks (jb*2+half), 256 thr = 4 waves, ~19.7 KB LDS -> 8 blk/CU.
// ---------------------------------------------------------------------------
__global__ __launch_bounds__(256, 8) void k3_pair(
    const float* __restrict__ u, const float* __restrict__ v,
    const u16* __restrict__ w3h, const u16* __restrict__ w3l,
    const float* __restrict__ mb1, const float* __restrict__ mb2,
    const float* __restrict__ mb3,
    float* __restrict__ Spart)
{
    __shared__ __align__(16) u16 Hh[64][72];
    __shared__ __align__(16) u16 Hl[64][72];
    __shared__ float us[64];
    __shared__ float Sp[4][64];

    const int t = threadIdx.x, lane = t & 63, w = t >> 6;
    const int jb = blockIdx.x >> 1, half = blockIdx.x & 1;
    const int b = jb & 15;
    const int l15 = lane & 15, quad = lane >> 4;
    const int m0 = w * 16;                      // wave's local i-strip

    if (t < 64) us[t] = u[jb * 64 + t];
    __syncthreads();

    // H1[iloc][ch] = lrelu(u[jb][ch] + v[(half*64+iloc)*16+b][ch]), wave-private
    #pragma unroll
    for (int n = 0; n < 4; ++n) {
        const int iloc = m0 + 4 * n + quad;
        const int ig   = half * 64 + iloc;
        const int c4   = l15 * 4;
        const float4 vv = *(const float4*)(v + (ig * 16 + b) * 64 + c4);
        const float4 uu = *(const float4*)(&us[c4]);
        float a0 = lrelu(vv.x + uu.x), a1 = lrelu(vv.y + uu.y);
        float a2 = lrelu(vv.z + uu.z), a3 = lrelu(vv.w + uu.w);
        ushort4 ph, pl;
        split_t(a0, ph.x, pl.x); split_t(a1, ph.y, pl.y);
        split_t(a2, ph.z, pl.z); split_t(a3, ph.w, pl.w);
        *(ushort4*)&Hh[iloc][c4] = ph;
        *(ushort4*)&Hl[iloc][c4] = pl;
    }

    const float* mbp[3] = {mb1, mb2, mb3};
    for (int layer = 0; layer < 3; ++layer) {
        const u16* wh = w3h + layer * 4096;
        const u16* wl = w3l + layer * 4096;
        floatx4 acc[4];                          // [mt = ch-tile], i-tile = 16
        #pragma unroll
        for (int i = 0; i < 4; ++i) acc[i] = (floatx4)0.0f;

        #pragma unroll
        for (int kc = 0; kc < 2; ++kc) {
            const int k0 = kc * 32 + quad * 8;
            const short8 bh = load_frag(&Hh[m0 + l15][k0]);
            const short8 bl = load_frag(&Hl[m0 + l15][k0]);
            #pragma unroll
            for (int mt = 0; mt < 4; ++mt) {
                const short8 ah = load_frag(wh + (mt * 16 + l15) * 64 + k0);
                const short8 al = load_frag(wl + (mt * 16 + l15) * 64 + k0);
                acc[mt] = mfma16(ah, bh, acc[mt]);
                acc[mt] = mfma16(ah, bl, acc[mt]);
                acc[mt] = mfma16(al, bh, acc[mt]);
            }
        }

        if (layer < 2) {
            // bias + lrelu + split, write back wave-private (no barrier)
            #pragma unroll
            for (int mt = 0; mt < 4; ++mt) {
                float bias[4];
                #pragma unroll
                for (int r = 0; r < 4; ++r) bias[r] = mbp[layer][mt * 16 + quad * 4 + r];
                const int i = m0 + l15;
                float v0 = lrelu(acc[mt][0] + bias[0]);
                float v1 = lrelu(acc[mt][1] + bias[1]);
                float v2 = lrelu(acc[mt][2] + bias[2]);
                float v3 = lrelu(acc[mt][3] + bias[3]);
                ushort4 ph, pl;
                split_t(v0, ph.x, pl.x); split_t(v1, ph.y, pl.y);
                split_t(v2, ph.z, pl.z); split_t(v3, ph.w, pl.w);
                *(ushort4*)&Hh[i][mt * 16 + quad * 4] = ph;
                *(ushort4*)&Hl[i][mt * 16 + quad * 4] = pl;
            }
        } else {
            // final layer: reduce over i (l15 lanes) in registers
            #pragma unroll
            for (int mt = 0; mt < 4; ++mt) {
                float sv[4];
                #pragma unroll
                for (int r = 0; r < 4; ++r) {
                    float val = lrelu(acc[mt][r] + mbp[2][mt * 16 + quad * 4 + r]);
                    val += __shfl_xor(val, 1, 16);
                    val += __shfl_xor(val, 2, 16);
                    val += __shfl_xor(val, 4, 16);
                    val += __shfl_xor(val, 8, 16);
                    sv[r] = val;
                }
                if (l15 == 0) {
                    const int ch = mt * 16 + quad * 4;
                    Sp[w][ch + 0] = sv[0]; Sp[w][ch + 1] = sv[1];
                    Sp[w][ch + 2] = sv[2]; Sp[w][ch + 3] = sv[3];
                }
            }
        }
    }

    __syncthreads();
    if (t < 64)
        Spart[jb * 128 + half * 64 + t] = Sp[0][t] + Sp[1][t] + Sp[2][t] + Sp[3][t];
}

// ---------------------------------------------------------------------------
// K4: head.  S = Spart[jb][0]+Spart[jb][1]; lrelu(S@lw0.T+lb0); @lw1.T+lb1.
// grid: 2048 single-wave blocks.
// ---------------------------------------------------------------------------
__global__ __launch_bounds__(64) void k4_head(
    const float* __restrict__ Spart,
    const float* __restrict__ lw0t, const float* __restrict__ lb0,
    const float* __restrict__ lw1t, const float* __restrict__ lb1,
    float* __restrict__ out)
{
    __shared__ float Ss[64];
    __shared__ float t1[64];
    const int t = threadIdx.x;
    const int jb = blockIdx.x;

    Ss[t] = Spart[jb * 128 + t] + Spart[jb * 128 + 64 + t];
    __syncthreads();

    float a = lb0[t];
    #pragma unroll 8
    for (int k = 0; k < 64; ++k) a += Ss[k] * lw0t[k * 64 + t];
    t1[t] = lrelu(a);
    __syncthreads();

    #pragma unroll
    for (int n = 0; n < 4; ++n) {
        const int c = t + 64 * n;
        float a2 = lb1[c];
        #pragma unroll 8
        for (int k = 0; k < 64; ++k) a2 += t1[k] * lw1t[k * 256 + c];
        out[jb * 256 + c] = lrelu(a2);
    }
}

// ---------------------------------------------------------------------------
extern "C" void kernel_launch(void* const* d_in, const int* in_sizes, int n_in,
                              void* d_out, int out_size, void* d_ws, size_t ws_size,
                              hipStream_t stream)
{
    const float* x   = (const float*)d_in[0];
    const float* cw0 = (const float*)d_in[1];
    const float* cb0 = (const float*)d_in[2];
    const float* cw1 = (const float*)d_in[3];
    const float* cb1 = (const float*)d_in[4];
    const float* cw2 = (const float*)d_in[5];
    const float* cb2 = (const float*)d_in[6];
    const float* cw3 = (const float*)d_in[7];
    const float* cb3 = (const float*)d_in[8];
    const float* mw0 = (const float*)d_in[9];
    const float* mb0 = (const float*)d_in[10];
    const float* mw1 = (const float*)d_in[11];
    const float* mb1 = (const float*)d_in[12];
    const float* mw2 = (const float*)d_in[13];
    const float* mb2 = (const float*)d_in[14];
    const float* mw3 = (const float*)d_in[15];
    const float* mb3 = (const float*)d_in[16];
    const float* lw0 = (const float*)d_in[17];
    const float* lb0 = (const float*)d_in[18];
    const float* lw1 = (const float*)d_in[19];
    const float* lb1 = (const float*)d_in[20];
    float* out = (float*)d_out;

    char* base = (char*)d_ws;
    u16* xh    = (u16*)(base + 0);
    u16* xl    = (u16*)(base + 2097152);
    u16* wch   = (u16*)(base + 4194304);
    u16* wcl   = (u16*)(base + 5242880);
    u16* b2h   = (u16*)(base + 6291456);
    u16* b2l   = (u16*)(base + 6356992);
    u16* w3h   = (u16*)(base + 6422528);
    u16* w3l   = (u16*)(base + 6447104);
    float* lw0t   = (float*)(base + 6471680);
    float* lw1t   = (float*)(base + 6488064);
    float* f_part = (float*)(base + 6553600);
    u16* Fh    = (u16*)(base + 14942208);
    u16* Fl    = (u16*)(base + 15990784);
    float* u   = (float*)(base + 17039360);
    float* v   = (float*)(base + 17563648);
    // Spart (1 MB) aliases f_part, which is dead after k1b consumes it.
    float* Spart = f_part;

    hipLaunchKernelGGL(p0_prep, dim3(6400), dim3(256), 0, stream,
                       x, cw0, cw1, cw2, cw3, mw0, mw1, mw2, mw3, lw0, lw1,
                       xh, xl, wch, wcl, b2h, b2l, w3h, w3l, lw0t, lw1t);
    hipLaunchKernelGGL(k1_conv, dim3(512), dim3(256), 0, stream,
                       xh, xl, wch, wcl, f_part);
    hipLaunchKernelGGL(k1b_act, dim3(512), dim3(256), 0, stream,
                       f_part, cb0, cb1, cb2, cb3, Fh, Fl);
    hipLaunchKernelGGL(k2_uv, dim3(128, 2), dim3(64), 0, stream,
                       Fh, Fl, b2h, b2l, mb0, u, v);
    hipLaunchKernelGGL(k3_pair, dim3(4096), dim3(256), 0, stream,
                       u, v, w3h, w3l, mb1, mb2, mb3, Spart);
    hipLaunchKernelGGL(k4_head, dim3(2048), dim3(64), 0, stream,
                       Spart, lw0t, lb0, lw1t, lb1, out);
}

// Round 5
// 189.079 us; speedup vs baseline: 1.4165x; 1.4165x over previous
//
#include <hip/hip_runtime.h>
#include <hip/hip_bf16.h>

#define SLOPE 0.1f
typedef unsigned short u16;
typedef unsigned int u32;
typedef __attribute__((ext_vector_type(8))) short short8;
typedef __attribute__((ext_vector_type(4))) float floatx4;

__device__ __forceinline__ float lrelu(float x) { return x > 0.0f ? x : SLOPE * x; }

// round-nearest split: x ~= hi + lo (bf16 each), rel err ~2^-17
__device__ __forceinline__ void split_rn(float x, u16* h, u16* l) {
    union { __hip_bfloat16 b; u16 u; } c1, c2;
    c1.b = __float2bfloat16(x);
    float hf = __bfloat162float(c1.b);
    c2.b = __float2bfloat16(x - hf);
    *h = c1.u; *l = c2.u;
}

// truncation split (cheap, ~2^-16 rel)
__device__ __forceinline__ void split_t(float x, u16& h, u16& l) {
    u32 ub = __float_as_uint(x);
    float hf = __uint_as_float(ub & 0xFFFF0000u);
    h = (u16)(ub >> 16);
    l = (u16)(__float_as_uint(x - hf) >> 16);
}

__device__ __forceinline__ short8 load_frag(const u16* p) {
    union { uint4 q; short8 s; } cv;
    cv.q = *(const uint4*)p;
    return cv.s;
}

__device__ __forceinline__ floatx4 mfma16(short8 a, short8 b, floatx4 c) {
    return __builtin_amdgcn_mfma_f32_16x16x32_bf16(a, b, c, 0, 0, 0);
}

// ---------------------------------------------------------------------------
// P0: one-shot preprocessing into FRAGMENT-LINEAR layouts.
// All MFMA operands stored as [tile...][kc][lane=quad*16+l15][j=0..7] u16 so
// kernels load them with lane-consecutive 16B chunks (fully coalesced).
//  seg0 xf   (1048576): x frags   [rt=128][kc=16][lane][8]
//  seg1 wcf  ( 524288): conv-w    [slot=16][nt=4][kc=16][lane][8]
//  seg2 b2f  (  32768): mw0 split [nh=2][nt=4][kc=8][lane][8]
//  seg3 w3f  (  12288): mw1..3    [layer=3][mt=4][kc=2][lane][8]
//  seg4 lw0t (   4096): fp32 transposed
//  seg5 lw1t (  16384): fp32 transposed
// total = 1638400 = 6400*256
// ---------------------------------------------------------------------------
__global__ __launch_bounds__(256) void p0_prep(
    const float* __restrict__ x,
    const float* __restrict__ cw0, const float* __restrict__ cw1,
    const float* __restrict__ cw2, const float* __restrict__ cw3,
    const float* __restrict__ mw0, const float* __restrict__ mw1,
    const float* __restrict__ mw2, const float* __restrict__ mw3,
    const float* __restrict__ lw0, const float* __restrict__ lw1,
    u16* __restrict__ xfh, u16* __restrict__ xfl,
    u16* __restrict__ wcfh, u16* __restrict__ wcfl,
    u16* __restrict__ b2fh, u16* __restrict__ b2fl,
    u16* __restrict__ w3fh, u16* __restrict__ w3fl,
    float* __restrict__ lw0t, float* __restrict__ lw1t)
{
    int idx = blockIdx.x * 256 + threadIdx.x;
    if (idx < 1048576) {
        const int j = idx & 7, lane = (idx >> 3) & 63;
        const int kc = (idx >> 9) & 15, rt = idx >> 13;
        const int l15 = lane & 15, quad = lane >> 4;
        split_rn(x[(rt * 16 + l15) * 512 + kc * 32 + quad * 8 + j], &xfh[idx], &xfl[idx]);
        return;
    }
    idx -= 1048576;
    if (idx < 524288) {
        const int j = idx & 7, lane = (idx >> 3) & 63;
        const int kc = (idx >> 9) & 15, nt = (idx >> 13) & 3, slot = idx >> 15;
        int branch, base;
        if (slot == 0)      { branch = 0; base = 0; }
        else if (slot < 4)  { branch = 1; base = 1; }
        else if (slot < 9)  { branch = 2; base = 4; }
        else                { branch = 3; base = 9; }
        const int dk = slot - base, ksz = 2 * branch + 1;
        const float* cw = branch == 0 ? cw0 : branch == 1 ? cw1 : branch == 2 ? cw2 : cw3;
        const int c = nt * 16 + (lane & 15);
        const int e = kc * 32 + (lane >> 4) * 8 + j;
        split_rn(cw[(c * ksz + dk) * 512 + e], &wcfh[idx], &wcfl[idx]);
        return;
    }
    idx -= 524288;
    if (idx < 32768) {
        const int j = idx & 7, lane = (idx >> 3) & 63;
        const int kc = (idx >> 9) & 7, nt = (idx >> 12) & 3, nh = idx >> 14;
        const int n = nh * 64 + nt * 16 + (lane & 15);
        const int k = kc * 32 + (lane >> 4) * 8 + j;
        split_rn(mw0[(n & 63) * 512 + (n >> 6) * 256 + k], &b2fh[idx], &b2fl[idx]);
        return;
    }
    idx -= 32768;
    if (idx < 12288) {
        const int j = idx & 7, lane = (idx >> 3) & 63;
        const int kc = (idx >> 9) & 1, mt = (idx >> 10) & 3, layer = idx >> 12;
        const float* mw = layer == 0 ? mw1 : layer == 1 ? mw2 : mw3;
        const int ch = mt * 16 + (lane & 15);
        const int k = kc * 32 + (lane >> 4) * 8 + j;
        split_rn(mw[ch * 64 + k], &w3fh[idx], &w3fl[idx]);
        return;
    }
    idx -= 12288;
    if (idx < 4096) { const int k = idx >> 6, n = idx & 63; lw0t[idx] = lw0[n * 64 + k]; return; }
    idx -= 4096;
    if (idx < 16384) { const int k = idx >> 8, n = idx & 255; lw1t[idx] = lw1[n * 64 + k]; return; }
}

// ---------------------------------------------------------------------------
// K1: per-(slot) conv-tap GEMM via MFMA; ALL loads frag-linear coalesced.
// grid: 512 blocks (slot*32 + tile), 256 thr = 4 waves; wave = 16 rows.
// ---------------------------------------------------------------------------
__global__ __launch_bounds__(256) void k1_conv(
    const u16* __restrict__ xfh, const u16* __restrict__ xfl,
    const u16* __restrict__ wcfh, const u16* __restrict__ wcfl,
    float* __restrict__ f_part)
{
    const int t = threadIdx.x, lane = t & 63, w = t >> 6;
    const int slot = blockIdx.x >> 5;
    const int m0 = (blockIdx.x & 31) * 64 + w * 16;
    int branch, base;
    if (slot == 0)      { branch = 0; base = 0; }
    else if (slot < 4)  { branch = 1; base = 1; }
    else if (slot < 9)  { branch = 2; base = 4; }
    else                { branch = 3; base = 9; }
    const int s = (slot - base) - branch;
    const int l15 = lane & 15, quad = lane >> 4;

    floatx4 acc[4];
    #pragma unroll
    for (int j = 0; j < 4; ++j) acc[j] = (floatx4)0.0f;

    const int gbase = m0 + s * 16;              // 16-aligned tile shift
    const bool ok = (gbase >= 0) && (gbase < 2048);
    const int rts = gbase >> 4;

    const short8 zfrag = {0, 0, 0, 0, 0, 0, 0, 0};
    #pragma unroll 4
    for (int kc = 0; kc < 16; ++kc) {
        short8 ah, al;
        if (ok) {
            const int aoff = ((rts * 16 + kc) * 64 + lane) * 8;
            ah = load_frag(xfh + aoff);
            al = load_frag(xfl + aoff);
        } else { ah = zfrag; al = zfrag; }
        #pragma unroll
        for (int nt = 0; nt < 4; ++nt) {
            const int boff = (((slot * 4 + nt) * 16 + kc) * 64 + lane) * 8;
            const short8 bh = load_frag(wcfh + boff);
            const short8 bl = load_frag(wcfl + boff);
            acc[nt] = mfma16(ah, bh, acc[nt]);
            acc[nt] = mfma16(ah, bl, acc[nt]);
            acc[nt] = mfma16(al, bh, acc[nt]);
        }
    }

    float* fp = f_part + slot * 131072;
    #pragma unroll
    for (int nt = 0; nt < 4; ++nt)
        #pragma unroll
        for (int r = 0; r < 4; ++r)
            fp[(m0 + quad * 4 + r) * 64 + nt * 16 + l15] = acc[nt][r];
}

// ---------------------------------------------------------------------------
// K1b: tap-sum + conv bias + lrelu -> F, written FRAG-LINEAR:
// Ff[rt=128][kc=8][lane][8].  131072 threads, 4 elems each.
// ---------------------------------------------------------------------------
__global__ __launch_bounds__(256) void k1b_act(
    const float* __restrict__ f_part,
    const float* __restrict__ cb0, const float* __restrict__ cb1,
    const float* __restrict__ cb2, const float* __restrict__ cb3,
    u16* __restrict__ Ffh, u16* __restrict__ Ffl)
{
    const int idx = blockIdx.x * 256 + threadIdx.x;   // 131072
    const int r = idx >> 6, m4 = (idx & 63) * 4;
    const int branch = m4 >> 6, c = m4 & 63;
    int base, ksz; const float* cb;
    if (branch == 0)      { base = 0; ksz = 1; cb = cb0; }
    else if (branch == 1) { base = 1; ksz = 3; cb = cb1; }
    else if (branch == 2) { base = 4; ksz = 5; cb = cb2; }
    else                  { base = 9; ksz = 7; cb = cb3; }
    float4 sum = *(const float4*)(cb + c);
    const float* fp = f_part + base * 131072 + r * 64 + c;
    for (int d = 0; d < ksz; ++d) {
        const float4 p = *(const float4*)(fp + d * 131072);
        sum.x += p.x; sum.y += p.y; sum.z += p.z; sum.w += p.w;
    }
    float v4[4] = {lrelu(sum.x), lrelu(sum.y), lrelu(sum.z), lrelu(sum.w)};
    u16 h4[4], l4[4];
    #pragma unroll
    for (int i = 0; i < 4; ++i) split_rn(v4[i], &h4[i], &l4[i]);
    // frag-linear dest: rt=r>>4, kc=m4>>5, lane=((m4>>3)&3)*16+(r&15), j0=m4&7
    const int dst = (((r >> 4) * 8 + (m4 >> 5)) * 64 + ((m4 >> 3) & 3) * 16 + (r & 15)) * 8 + (m4 & 7);
    *(ushort4*)(Ffh + dst) = make_ushort4(h4[0], h4[1], h4[2], h4[3]);
    *(ushort4*)(Ffl + dst) = make_ushort4(l4[0], l4[1], l4[2], l4[3]);
}

// ---------------------------------------------------------------------------
// K2: [u|v] = F @ B2^T via MFMA; all loads frag-linear coalesced.
// grid: (128, 2), 64 thr (1 wave): wave = 16 rows x 64 cols.
// ---------------------------------------------------------------------------
__global__ __launch_bounds__(64) void k2_uv(
    const u16* __restrict__ Ffh, const u16* __restrict__ Ffl,
    const u16* __restrict__ b2fh, const u16* __restrict__ b2fl,
    const float* __restrict__ mb0,
    float* __restrict__ u, float* __restrict__ v)
{
    const int lane = threadIdx.x & 63;
    const int rt = blockIdx.x;
    const int nh = blockIdx.y;
    const int l15 = lane & 15, quad = lane >> 4;

    floatx4 acc[4];
    #pragma unroll
    for (int j = 0; j < 4; ++j) acc[j] = (floatx4)0.0f;

    #pragma unroll 4
    for (int kc = 0; kc < 8; ++kc) {
        const int aoff = ((rt * 8 + kc) * 64 + lane) * 8;
        const short8 ah = load_frag(Ffh + aoff);
        const short8 al = load_frag(Ffl + aoff);
        #pragma unroll
        for (int nt = 0; nt < 4; ++nt) {
            const int boff = (((nh * 4 + nt) * 8 + kc) * 64 + lane) * 8;
            const short8 bh = load_frag(b2fh + boff);
            const short8 bl = load_frag(b2fl + boff);
            acc[nt] = mfma16(ah, bh, acc[nt]);
            acc[nt] = mfma16(ah, bl, acc[nt]);
            acc[nt] = mfma16(al, bh, acc[nt]);
        }
    }

    #pragma unroll
    for (int nt = 0; nt < 4; ++nt) {
        const int c = nt * 16 + l15;
        #pragma unroll
        for (int r = 0; r < 4; ++r) {
            const int row = rt * 16 + quad * 4 + r;
            const float val = acc[nt][r];
            if (nh == 0) u[row * 64 + c] = val + mb0[c];
            else         v[row * 64 + c] = val;
        }
    }
}

// ---------------------------------------------------------------------------
// K3: one block per jb, 2 waves x 64 i's.  H in LDS bf16 hi/lo (wave-private
// -> zero inter-layer barriers).  Per layer: 16 coalesced A-loads (w3f) +
// 16 LDS B-reads feed 96 MFMAs.  Layer-3 reduced over i in registers (shfl),
// head (64->64->256) fused at the end.
// grid: 2048 blocks, 128 thr; LDS ~38 KB -> 4 blocks/CU.
// ---------------------------------------------------------------------------
__global__ __launch_bounds__(128, 2) void k3_pair(
    const float* __restrict__ u, const float* __restrict__ v,
    const u16* __restrict__ w3fh, const u16* __restrict__ w3fl,
    const float* __restrict__ mb1, const float* __restrict__ mb2,
    const float* __restrict__ mb3,
    const float* __restrict__ lw0t, const float* __restrict__ lb0,
    const float* __restrict__ lw1t, const float* __restrict__ lb1,
    float* __restrict__ out)
{
    __shared__ __align__(16) u16 Hh[128][72];
    __shared__ __align__(16) u16 Hl[128][72];
    __shared__ float us[64];
    __shared__ float Sp[2][64];
    __shared__ float Ss[64];
    __shared__ float t1[64];

    const int t = threadIdx.x, lane = t & 63, w = t >> 6;   // w in {0,1}
    const int jb = blockIdx.x, b = jb & 15;
    const int l15 = lane & 15, quad = lane >> 4;
    const int i0 = w * 64;                       // wave's i-strip (64 i's)

    if (t < 64) us[t] = u[jb * 64 + t];
    __syncthreads();

    // H1[i][ch] = lrelu(u[jb][ch] + v[i*16+b][ch]), wave-private rows
    #pragma unroll
    for (int n = 0; n < 16; ++n) {
        const int i  = i0 + 4 * n + quad;
        const int c4 = l15 * 4;
        const float4 vv = *(const float4*)(v + (i * 16 + b) * 64 + c4);
        const float4 uu = *(const float4*)(&us[c4]);
        float a0 = lrelu(vv.x + uu.x), a1 = lrelu(vv.y + uu.y);
        float a2 = lrelu(vv.z + uu.z), a3 = lrelu(vv.w + uu.w);
        ushort4 ph, pl;
        split_t(a0, ph.x, pl.x); split_t(a1, ph.y, pl.y);
        split_t(a2, ph.z, pl.z); split_t(a3, ph.w, pl.w);
        *(ushort4*)&Hh[i][c4] = ph;
        *(ushort4*)&Hl[i][c4] = pl;
    }

    const float* mbp[3] = {mb1, mb2, mb3};
    for (int layer = 0; layer < 3; ++layer) {
        floatx4 acc[4][4];                       // [mt=ch][nt=i]
        #pragma unroll
        for (int i = 0; i < 4; ++i)
            #pragma unroll
            for (int j = 0; j < 4; ++j) acc[i][j] = (floatx4)0.0f;

        #pragma unroll
        for (int kc = 0; kc < 2; ++kc) {
            // coalesced A-frags (weights) for this kc
            short8 ah[4], al[4];
            #pragma unroll
            for (int mt = 0; mt < 4; ++mt) {
                const int aoff = (((layer * 4 + mt) * 2 + kc) * 64 + lane) * 8;
                ah[mt] = load_frag(w3fh + aoff);
                al[mt] = load_frag(w3fl + aoff);
            }
            const int k0 = kc * 32 + quad * 8;
            #pragma unroll
            for (int nt = 0; nt < 4; ++nt) {
                const short8 bh = load_frag(&Hh[i0 + nt * 16 + l15][k0]);
                const short8 bl = load_frag(&Hl[i0 + nt * 16 + l15][k0]);
                #pragma unroll
                for (int mt = 0; mt < 4; ++mt) {
                    acc[mt][nt] = mfma16(ah[mt], bh, acc[mt][nt]);
                    acc[mt][nt] = mfma16(ah[mt], bl, acc[mt][nt]);
                    acc[mt][nt] = mfma16(al[mt], bh, acc[mt][nt]);
                }
            }
        }

        if (layer < 2) {
            #pragma unroll
            for (int mt = 0; mt < 4; ++mt) {
                float bias[4];
                #pragma unroll
                for (int r = 0; r < 4; ++r) bias[r] = mbp[layer][mt * 16 + quad * 4 + r];
                #pragma unroll
                for (int nt = 0; nt < 4; ++nt) {
                    const int i = i0 + nt * 16 + l15;
                    float v0 = lrelu(acc[mt][nt][0] + bias[0]);
                    float v1 = lrelu(acc[mt][nt][1] + bias[1]);
                    float v2 = lrelu(acc[mt][nt][2] + bias[2]);
                    float v3 = lrelu(acc[mt][nt][3] + bias[3]);
                    ushort4 ph, pl;
                    split_t(v0, ph.x, pl.x); split_t(v1, ph.y, pl.y);
                    split_t(v2, ph.z, pl.z); split_t(v3, ph.w, pl.w);
                    *(ushort4*)&Hh[i][mt * 16 + quad * 4] = ph;
                    *(ushort4*)&Hl[i][mt * 16 + quad * 4] = pl;
                }
            }
        } else {
            // final layer: lrelu + reduce over i (nt in regs, l15 via shfl)
            #pragma unroll
            for (int mt = 0; mt < 4; ++mt) {
                float bias[4];
                #pragma unroll
                for (int r = 0; r < 4; ++r) bias[r] = mbp[2][mt * 16 + quad * 4 + r];
                float sv[4];
                #pragma unroll
                for (int r = 0; r < 4; ++r) {
                    float val = lrelu(acc[mt][0][r] + bias[r])
                              + lrelu(acc[mt][1][r] + bias[r])
                              + lrelu(acc[mt][2][r] + bias[r])
                              + lrelu(acc[mt][3][r] + bias[r]);
                    val += __shfl_xor(val, 1, 16);
                    val += __shfl_xor(val, 2, 16);
                    val += __shfl_xor(val, 4, 16);
                    val += __shfl_xor(val, 8, 16);
                    sv[r] = val;
                }
                if (l15 == 0) {
                    const int ch = mt * 16 + quad * 4;
                    Sp[w][ch + 0] = sv[0]; Sp[w][ch + 1] = sv[1];
                    Sp[w][ch + 2] = sv[2]; Sp[w][ch + 3] = sv[3];
                }
            }
        }
    }

    __syncthreads();
    if (t < 64) Ss[t] = Sp[0][t] + Sp[1][t];
    __syncthreads();

    // head layer 1: 64 -> 64
    if (t < 64) {
        float a = lb0[t];
        #pragma unroll 8
        for (int k = 0; k < 64; ++k) a += Ss[k] * lw0t[k * 64 + t];
        t1[t] = lrelu(a);
    }
    __syncthreads();

    // head layer 2: 64 -> 256 (two outputs per thread)
    #pragma unroll
    for (int n = 0; n < 2; ++n) {
        const int c = t + 128 * n;
        float a = lb1[c];
        #pragma unroll 8
        for (int k = 0; k < 64; ++k) a += t1[k] * lw1t[k * 256 + c];
        out[jb * 256 + c] = lrelu(a);
    }
}

// ---------------------------------------------------------------------------
extern "C" void kernel_launch(void* const* d_in, const int* in_sizes, int n_in,
                              void* d_out, int out_size, void* d_ws, size_t ws_size,
                              hipStream_t stream)
{
    const float* x   = (const float*)d_in[0];
    const float* cw0 = (const float*)d_in[1];
    const float* cb0 = (const float*)d_in[2];
    const float* cw1 = (const float*)d_in[3];
    const float* cb1 = (const float*)d_in[4];
    const float* cw2 = (const float*)d_in[5];
    const float* cb2 = (const float*)d_in[6];
    const float* cw3 = (const float*)d_in[7];
    const float* cb3 = (const float*)d_in[8];
    const float* mw0 = (const float*)d_in[9];
    const float* mb0 = (const float*)d_in[10];
    const float* mw1 = (const float*)d_in[11];
    const float* mb1 = (const float*)d_in[12];
    const float* mw2 = (const float*)d_in[13];
    const float* mb2 = (const float*)d_in[14];
    const float* mw3 = (const float*)d_in[15];
    const float* mb3 = (const float*)d_in[16];
    const float* lw0 = (const float*)d_in[17];
    const float* lb0 = (const float*)d_in[18];
    const float* lw1 = (const float*)d_in[19];
    const float* lb1 = (const float*)d_in[20];
    float* out = (float*)d_out;

    char* base = (char*)d_ws;
    u16* xfh   = (u16*)(base + 0);
    u16* xfl   = (u16*)(base + 2097152);
    u16* wcfh  = (u16*)(base + 4194304);
    u16* wcfl  = (u16*)(base + 5242880);
    u16* b2fh  = (u16*)(base + 6291456);
    u16* b2fl  = (u16*)(base + 6356992);
    u16* w3fh  = (u16*)(base + 6422528);
    u16* w3fl  = (u16*)(base + 6447104);
    float* lw0t   = (float*)(base + 6471680);
    float* lw1t   = (float*)(base + 6488064);
    float* f_part = (float*)(base + 6553600);
    u16* Ffh   = (u16*)(base + 14942208);
    u16* Ffl   = (u16*)(base + 15990784);
    float* u   = (float*)(base + 17039360);
    float* v   = (float*)(base + 17563648);
    // total 18087936 bytes

    hipLaunchKernelGGL(p0_prep, dim3(6400), dim3(256), 0, stream,
                       x, cw0, cw1, cw2, cw3, mw0, mw1, mw2, mw3, lw0, lw1,
                       xfh, xfl, wcfh, wcfl, b2fh, b2fl, w3fh, w3fl, lw0t, lw1t);
    hipLaunchKernelGGL(k1_conv, dim3(512), dim3(256), 0, stream,
                       xfh, xfl, wcfh, wcfl, f_part);
    hipLaunchKernelGGL(k1b_act, dim3(512), dim3(256), 0, stream,
                       f_part, cb0, cb1, cb2, cb3, Ffh, Ffl);
    hipLaunchKernelGGL(k2_uv, dim3(128, 2), dim3(64), 0, stream,
                       Ffh, Ffl, b2fh, b2fl, mb0, u, v);
    hipLaunchKernelGGL(k3_pair, dim3(2048), dim3(128), 0, stream,
                       u, v, w3fh, w3fl, mb1, mb2, mb3, lw0t, lb0, lw1t, lb1, out);
}

// Round 6
// 185.786 us; speedup vs baseline: 1.4416x; 1.0177x over previous
//
#include <hip/hip_runtime.h>
#include <hip/hip_bf16.h>

#define SLOPE 0.1f
typedef unsigned short u16;
typedef unsigned int u32;
typedef __attribute__((ext_vector_type(8))) short short8;
typedef __attribute__((ext_vector_type(4))) float floatx4;

__device__ __forceinline__ float lrelu(float x) { return x > 0.0f ? x : SLOPE * x; }

// round-nearest split: x ~= hi + lo (bf16 each), rel err ~2^-17
__device__ __forceinline__ void split_rn(float x, u16* h, u16* l) {
    union { __hip_bfloat16 b; u16 u; } c1, c2;
    c1.b = __float2bfloat16(x);
    float hf = __bfloat162float(c1.b);
    c2.b = __float2bfloat16(x - hf);
    *h = c1.u; *l = c2.u;
}

// truncation split of a PAIR of fp32 -> packed hi-u32 and lo-u32 (v_perm pack)
__device__ __forceinline__ void pack2x2(float v0, float v1, u32& h, u32& l) {
    u32 a0 = __float_as_uint(v0), a1 = __float_as_uint(v1);
    h = __builtin_amdgcn_perm(a1, a0, 0x07060302u);   // [a0.hi16 | a1.hi16]
    float r0 = v0 - __uint_as_float(a0 & 0xFFFF0000u);
    float r1 = v1 - __uint_as_float(a1 & 0xFFFF0000u);
    l = __builtin_amdgcn_perm(__float_as_uint(r1), __float_as_uint(r0), 0x07060302u);
}

__device__ __forceinline__ short8 load_frag(const u16* p) {
    union { uint4 q; short8 s; } cv;
    cv.q = *(const uint4*)p;
    return cv.s;
}

__device__ __forceinline__ floatx4 mfma16(short8 a, short8 b, floatx4 c) {
    return __builtin_amdgcn_mfma_f32_16x16x32_bf16(a, b, c, 0, 0, 0);
}

// ---------------------------------------------------------------------------
// P0: one-shot preprocessing into FRAGMENT-LINEAR layouts (same as R5).
//  seg0 xf   (1048576): x frags   [rt=128][kc=16][lane][8]
//  seg1 wcf  ( 524288): conv-w    [slot=16][nt=4][kc=16][lane][8]
//  seg2 b2f  (  32768): mw0 split [nh=2][nt=4][kc=8][lane][8]
//  seg3 w3f  (  12288): mw1..3    [layer=3][mt=4][kc=2][lane][8]
//  seg4 lw0t (   4096): fp32 transposed
//  seg5 lw1t (  16384): fp32 transposed
// ---------------------------------------------------------------------------
__global__ __launch_bounds__(256) void p0_prep(
    const float* __restrict__ x,
    const float* __restrict__ cw0, const float* __restrict__ cw1,
    const float* __restrict__ cw2, const float* __restrict__ cw3,
    const float* __restrict__ mw0, const float* __restrict__ mw1,
    const float* __restrict__ mw2, const float* __restrict__ mw3,
    const float* __restrict__ lw0, const float* __restrict__ lw1,
    u16* __restrict__ xfh, u16* __restrict__ xfl,
    u16* __restrict__ wcfh, u16* __restrict__ wcfl,
    u16* __restrict__ b2fh, u16* __restrict__ b2fl,
    u16* __restrict__ w3fh, u16* __restrict__ w3fl,
    float* __restrict__ lw0t, float* __restrict__ lw1t)
{
    int idx = blockIdx.x * 256 + threadIdx.x;
    if (idx < 1048576) {
        const int j = idx & 7, lane = (idx >> 3) & 63;
        const int kc = (idx >> 9) & 15, rt = idx >> 13;
        const int l15 = lane & 15, quad = lane >> 4;
        split_rn(x[(rt * 16 + l15) * 512 + kc * 32 + quad * 8 + j], &xfh[idx], &xfl[idx]);
        return;
    }
    idx -= 1048576;
    if (idx < 524288) {
        const int j = idx & 7, lane = (idx >> 3) & 63;
        const int kc = (idx >> 9) & 15, nt = (idx >> 13) & 3, slot = idx >> 15;
        int branch, base;
        if (slot == 0)      { branch = 0; base = 0; }
        else if (slot < 4)  { branch = 1; base = 1; }
        else if (slot < 9)  { branch = 2; base = 4; }
        else                { branch = 3; base = 9; }
        const int dk = slot - base, ksz = 2 * branch + 1;
        const float* cw = branch == 0 ? cw0 : branch == 1 ? cw1 : branch == 2 ? cw2 : cw3;
        const int c = nt * 16 + (lane & 15);
        const int e = kc * 32 + (lane >> 4) * 8 + j;
        split_rn(cw[(c * ksz + dk) * 512 + e], &wcfh[idx], &wcfl[idx]);
        return;
    }
    idx -= 524288;
    if (idx < 32768) {
        const int j = idx & 7, lane = (idx >> 3) & 63;
        const int kc = (idx >> 9) & 7, nt = (idx >> 12) & 3, nh = idx >> 14;
        const int n = nh * 64 + nt * 16 + (lane & 15);
        const int k = kc * 32 + (lane >> 4) * 8 + j;
        split_rn(mw0[(n & 63) * 512 + (n >> 6) * 256 + k], &b2fh[idx], &b2fl[idx]);
        return;
    }
    idx -= 32768;
    if (idx < 12288) {
        const int j = idx & 7, lane = (idx >> 3) & 63;
        const int kc = (idx >> 9) & 1, mt = (idx >> 10) & 3, layer = idx >> 12;
        const float* mw = layer == 0 ? mw1 : layer == 1 ? mw2 : mw3;
        const int ch = mt * 16 + (lane & 15);
        const int k = kc * 32 + (lane >> 4) * 8 + j;
        split_rn(mw[ch * 64 + k], &w3fh[idx], &w3fl[idx]);
        return;
    }
    idx -= 12288;
    if (idx < 4096) { const int k = idx >> 6, n = idx & 63; lw0t[idx] = lw0[n * 64 + k]; return; }
    idx -= 4096;
    if (idx < 16384) { const int k = idx >> 8, n = idx & 255; lw1t[idx] = lw1[n * 64 + k]; return; }
}

// ---------------------------------------------------------------------------
// K1f: fused conv GEMM: per (row-tile rt, branch br) accumulate over ALL taps
// in AGPRs (K = ksz*16 kc-units split round-robin over 4 waves), LDS-reduce,
// then bias + lrelu + split -> F written FRAG-LINEAR.  f_part/k1b eliminated.
// grid: (128, 4), 256 thr.
// ---------------------------------------------------------------------------
__global__ __launch_bounds__(256) void k1f_conv(
    const u16* __restrict__ xfh, const u16* __restrict__ xfl,
    const u16* __restrict__ wcfh, const u16* __restrict__ wcfl,
    const float* __restrict__ cb0, const float* __restrict__ cb1,
    const float* __restrict__ cb2, const float* __restrict__ cb3,
    u16* __restrict__ Ffh, u16* __restrict__ Ffl)
{
    __shared__ float P[4][16][72];

    const int t = threadIdx.x, lane = t & 63, w = t >> 6;
    const int rt = blockIdx.x;                 // 0..127
    const int br = blockIdx.y;                 // 0..3
    const int base = br * br;                  // 0,1,4,9
    const int ksz = 2 * br + 1;
    const int l15 = lane & 15, quad = lane >> 4;

    floatx4 acc[4];
    #pragma unroll
    for (int j = 0; j < 4; ++j) acc[j] = (floatx4)0.0f;

    const int nunits = ksz * 16;
    for (int unit = w; unit < nunits; unit += 4) {
        const int dk = unit >> 4, kc = unit & 15;
        const int rts = rt + dk - br;          // tap shift in whole 16-row tiles
        if (rts < 0 || rts >= 128) continue;
        const int aoff = ((rts * 16 + kc) * 64 + lane) * 8;
        const short8 ah = load_frag(xfh + aoff);
        const short8 al = load_frag(xfl + aoff);
        const int slot = base + dk;
        #pragma unroll
        for (int nt = 0; nt < 4; ++nt) {
            const int boff = (((slot * 4 + nt) * 16 + kc) * 64 + lane) * 8;
            const short8 bh = load_frag(wcfh + boff);
            const short8 bl = load_frag(wcfl + boff);
            acc[nt] = mfma16(ah, bh, acc[nt]);
            acc[nt] = mfma16(ah, bl, acc[nt]);
            acc[nt] = mfma16(al, bh, acc[nt]);
        }
    }

    #pragma unroll
    for (int nt = 0; nt < 4; ++nt)
        #pragma unroll
        for (int r = 0; r < 4; ++r)
            P[w][quad * 4 + r][nt * 16 + l15] = acc[nt][r];
    __syncthreads();

    // reduce 4 waves + bias + lrelu + split -> frag-linear F
    const float* cb = br == 0 ? cb0 : br == 1 ? cb1 : br == 2 ? cb2 : cb3;
    const int row = t >> 4, c4 = (t & 15) * 4;
    u16 h4[4], l4[4];
    #pragma unroll
    for (int i = 0; i < 4; ++i) {
        float val = P[0][row][c4 + i] + P[1][row][c4 + i]
                  + P[2][row][c4 + i] + P[3][row][c4 + i] + cb[c4 + i];
        split_rn(lrelu(val), &h4[i], &l4[i]);
    }
    const int m4 = br * 64 + c4;
    const int dst = ((rt * 8 + (m4 >> 5)) * 64 + ((m4 >> 3) & 3) * 16 + row) * 8 + (m4 & 7);
    *(ushort4*)(Ffh + dst) = make_ushort4(h4[0], h4[1], h4[2], h4[3]);
    *(ushort4*)(Ffl + dst) = make_ushort4(l4[0], l4[1], l4[2], l4[3]);
}

// ---------------------------------------------------------------------------
// K2: [u|v] = F @ B2^T, K split over 4 waves (wave = (nh, kc-group of 4)),
// LDS reduce, u gets +mb0, v written TRANSPOSED (b-major) as v_t for k3.
// grid: 128 blocks, 256 thr.
// ---------------------------------------------------------------------------
__global__ __launch_bounds__(256) void k2_uv(
    const u16* __restrict__ Ffh, const u16* __restrict__ Ffl,
    const u16* __restrict__ b2fh, const u16* __restrict__ b2fl,
    const float* __restrict__ mb0,
    float* __restrict__ u, float* __restrict__ v_t)
{
    __shared__ float P[4][16][72];

    const int t = threadIdx.x, lane = t & 63, w = t >> 6;
    const int rt = blockIdx.x;
    const int nh = w >> 1, kg = w & 1;
    const int l15 = lane & 15, quad = lane >> 4;

    floatx4 acc[4];
    #pragma unroll
    for (int j = 0; j < 4; ++j) acc[j] = (floatx4)0.0f;

    #pragma unroll
    for (int kk = 0; kk < 4; ++kk) {
        const int kc = kg * 4 + kk;
        const int aoff = ((rt * 8 + kc) * 64 + lane) * 8;
        const short8 ah = load_frag(Ffh + aoff);
        const short8 al = load_frag(Ffl + aoff);
        #pragma unroll
        for (int nt = 0; nt < 4; ++nt) {
            const int boff = (((nh * 4 + nt) * 8 + kc) * 64 + lane) * 8;
            const short8 bh = load_frag(b2fh + boff);
            const short8 bl = load_frag(b2fl + boff);
            acc[nt] = mfma16(ah, bh, acc[nt]);
            acc[nt] = mfma16(ah, bl, acc[nt]);
            acc[nt] = mfma16(al, bh, acc[nt]);
        }
    }

    #pragma unroll
    for (int nt = 0; nt < 4; ++nt)
        #pragma unroll
        for (int r = 0; r < 4; ++r)
            P[w][quad * 4 + r][nt * 16 + l15] = acc[nt][r];
    __syncthreads();

    const int row = t >> 4, c4 = (t & 15) * 4;
    const int rglob = rt * 16 + row;
    const int i = rglob >> 4, b = rglob & 15;
    float4 uu, vv;
    uu.x = P[0][row][c4 + 0] + P[1][row][c4 + 0] + mb0[c4 + 0];
    uu.y = P[0][row][c4 + 1] + P[1][row][c4 + 1] + mb0[c4 + 1];
    uu.z = P[0][row][c4 + 2] + P[1][row][c4 + 2] + mb0[c4 + 2];
    uu.w = P[0][row][c4 + 3] + P[1][row][c4 + 3] + mb0[c4 + 3];
    vv.x = P[2][row][c4 + 0] + P[3][row][c4 + 0];
    vv.y = P[2][row][c4 + 1] + P[3][row][c4 + 1];
    vv.z = P[2][row][c4 + 2] + P[3][row][c4 + 2];
    vv.w = P[2][row][c4 + 3] + P[3][row][c4 + 3];
    *(float4*)(u + rglob * 64 + c4) = uu;
    *(float4*)(v_t + (b * 128 + i) * 64 + c4) = vv;
}

// ---------------------------------------------------------------------------
// K3: per jb, 2 waves x 64 i's; H bf16 hi/lo in LDS, wave-private (no
// inter-layer barriers).  Coalesced v_t loads, frag-linear weights, v_perm
// packed epilogue.  Layer-3 reduced over i in regs (shfl) -> Spart halves.
// grid: 2048 blocks, 128 thr; LDS ~37 KB -> 4 blocks/CU.
// ---------------------------------------------------------------------------
__global__ __launch_bounds__(128, 2) void k3_pair(
    const float* __restrict__ u, const float* __restrict__ v_t,
    const u16* __restrict__ w3fh, const u16* __restrict__ w3fl,
    const float* __restrict__ mb1, const float* __restrict__ mb2,
    const float* __restrict__ mb3,
    float* __restrict__ Spart)
{
    __shared__ __align__(16) u16 Hh[128][72];
    __shared__ __align__(16) u16 Hl[128][72];
    __shared__ __align__(16) float us[64];

    const int t = threadIdx.x, lane = t & 63, w = t >> 6;   // w in {0,1}
    const int jb = blockIdx.x, b = jb & 15;
    const int l15 = lane & 15, quad = lane >> 4;
    const int i0 = w * 64;

    if (t < 64) us[t] = u[jb * 64 + t];
    __syncthreads();

    // H1 build: contiguous 16 KB stream per wave from v_t
    const float* vb = v_t + (b * 128 + i0) * 64;
    #pragma unroll
    for (int n = 0; n < 16; ++n) {
        const int idx = n * 64 + lane;
        const int il = idx >> 4, c4 = (idx & 15) * 4;
        const float4 vv = *(const float4*)(vb + idx * 4);
        const float4 uu = *(const float4*)(&us[c4]);
        const float a0 = lrelu(vv.x + uu.x), a1 = lrelu(vv.y + uu.y);
        const float a2 = lrelu(vv.z + uu.z), a3 = lrelu(vv.w + uu.w);
        u32 h01, l01, h23, l23;
        pack2x2(a0, a1, h01, l01);
        pack2x2(a2, a3, h23, l23);
        *(uint2*)&Hh[i0 + il][c4] = make_uint2(h01, h23);
        *(uint2*)&Hl[i0 + il][c4] = make_uint2(l01, l23);
    }

    const float* mbp[3] = {mb1, mb2, mb3};
    for (int layer = 0; layer < 3; ++layer) {
        floatx4 acc[4][4];                       // [mt=ch][nt=i]
        #pragma unroll
        for (int i = 0; i < 4; ++i)
            #pragma unroll
            for (int j = 0; j < 4; ++j) acc[i][j] = (floatx4)0.0f;

        #pragma unroll
        for (int kc = 0; kc < 2; ++kc) {
            short8 ah[4], al[4];
            #pragma unroll
            for (int mt = 0; mt < 4; ++mt) {
                const int aoff = (((layer * 4 + mt) * 2 + kc) * 64 + lane) * 8;
                ah[mt] = load_frag(w3fh + aoff);
                al[mt] = load_frag(w3fl + aoff);
            }
            const int k0 = kc * 32 + quad * 8;
            #pragma unroll
            for (int nt = 0; nt < 4; ++nt) {
                const short8 bh = load_frag(&Hh[i0 + nt * 16 + l15][k0]);
                const short8 bl = load_frag(&Hl[i0 + nt * 16 + l15][k0]);
                #pragma unroll
                for (int mt = 0; mt < 4; ++mt) {
                    acc[mt][nt] = mfma16(ah[mt], bh, acc[mt][nt]);
                    acc[mt][nt] = mfma16(ah[mt], bl, acc[mt][nt]);
                    acc[mt][nt] = mfma16(al[mt], bh, acc[mt][nt]);
                }
            }
        }

        if (layer < 2) {
            #pragma unroll
            for (int mt = 0; mt < 4; ++mt) {
                float bias[4];
                #pragma unroll
                for (int r = 0; r < 4; ++r) bias[r] = mbp[layer][mt * 16 + quad * 4 + r];
                #pragma unroll
                for (int nt = 0; nt < 4; ++nt) {
                    const int i = i0 + nt * 16 + l15;
                    const float v0 = lrelu(acc[mt][nt][0] + bias[0]);
                    const float v1 = lrelu(acc[mt][nt][1] + bias[1]);
                    const float v2 = lrelu(acc[mt][nt][2] + bias[2]);
                    const float v3 = lrelu(acc[mt][nt][3] + bias[3]);
                    u32 h01, l01, h23, l23;
                    pack2x2(v0, v1, h01, l01);
                    pack2x2(v2, v3, h23, l23);
                    *(uint2*)&Hh[i][mt * 16 + quad * 4] = make_uint2(h01, h23);
                    *(uint2*)&Hl[i][mt * 16 + quad * 4] = make_uint2(l01, l23);
                }
            }
        } else {
            // final layer: lrelu + reduce over all 64 i of this wave
            #pragma unroll
            for (int mt = 0; mt < 4; ++mt) {
                float bias[4];
                #pragma unroll
                for (int r = 0; r < 4; ++r) bias[r] = mbp[2][mt * 16 + quad * 4 + r];
                float4 sv;
                #pragma unroll
                for (int r = 0; r < 4; ++r) {
                    float val = lrelu(acc[mt][0][r] + bias[r])
                              + lrelu(acc[mt][1][r] + bias[r])
                              + lrelu(acc[mt][2][r] + bias[r])
                              + lrelu(acc[mt][3][r] + bias[r]);
                    val += __shfl_xor(val, 1, 16);
                    val += __shfl_xor(val, 2, 16);
                    val += __shfl_xor(val, 4, 16);
                    val += __shfl_xor(val, 8, 16);
                    (&sv.x)[r] = val;
                }
                if (l15 == 0)
                    *(float4*)(Spart + jb * 128 + w * 64 + mt * 16 + quad * 4) = sv;
            }
        }
    }
}

// ---------------------------------------------------------------------------
// K4: head over 8 jb per block (weight loads amortized & coalesced).
// S = Spart halves summed; T1 = lrelu(S@lw0.T+lb0); out = lrelu(T1@lw1.T+lb1).
// grid: 256 blocks, 256 thr.
// ---------------------------------------------------------------------------
__global__ __launch_bounds__(256) void k4_head(
    const float* __restrict__ Spart,
    const float* __restrict__ lw0t, const float* __restrict__ lb0,
    const float* __restrict__ lw1t, const float* __restrict__ lb1,
    float* __restrict__ out)
{
    __shared__ float Ss[8][64];
    __shared__ float T1[8][64];

    const int t = threadIdx.x;
    const int jb0 = blockIdx.x * 8;

    #pragma unroll
    for (int p = 0; p < 2; ++p) {
        const int idx = t + 256 * p;
        const int jbb = idx >> 6, ch = idx & 63;
        Ss[jbb][ch] = Spart[(jb0 + jbb) * 128 + ch] + Spart[(jb0 + jbb) * 128 + 64 + ch];
    }
    __syncthreads();

    #pragma unroll
    for (int p = 0; p < 2; ++p) {
        const int idx = t + 256 * p;
        const int jbb = idx >> 6, c = idx & 63;
        float a = lb0[c];
        #pragma unroll 8
        for (int k = 0; k < 64; ++k) a += Ss[jbb][k] * lw0t[k * 64 + c];
        T1[jbb][c] = lrelu(a);
    }
    __syncthreads();

    const int c = t;
    float acc[8];
    const float base = lb1[c];
    #pragma unroll
    for (int jbb = 0; jbb < 8; ++jbb) acc[jbb] = base;
    #pragma unroll 4
    for (int k = 0; k < 64; ++k) {
        const float wv = lw1t[k * 256 + c];
        #pragma unroll
        for (int jbb = 0; jbb < 8; ++jbb) acc[jbb] += T1[jbb][k] * wv;
    }
    #pragma unroll
    for (int jbb = 0; jbb < 8; ++jbb)
        out[(jb0 + jbb) * 256 + c] = lrelu(acc[jbb]);
}

// ---------------------------------------------------------------------------
extern "C" void kernel_launch(void* const* d_in, const int* in_sizes, int n_in,
                              void* d_out, int out_size, void* d_ws, size_t ws_size,
                              hipStream_t stream)
{
    const float* x   = (const float*)d_in[0];
    const float* cw0 = (const float*)d_in[1];
    const float* cb0 = (const float*)d_in[2];
    const float* cw1 = (const float*)d_in[3];
    const float* cb1 = (const float*)d_in[4];
    const float* cw2 = (const float*)d_in[5];
    const float* cb2 = (const float*)d_in[6];
    const float* cw3 = (const float*)d_in[7];
    const float* cb3 = (const float*)d_in[8];
    const float* mw0 = (const float*)d_in[9];
    const float* mb0 = (const float*)d_in[10];
    const float* mw1 = (const float*)d_in[11];
    const float* mb1 = (const float*)d_in[12];
    const float* mw2 = (const float*)d_in[13];
    const float* mb2 = (const float*)d_in[14];
    const float* mw3 = (const float*)d_in[15];
    const float* mb3 = (const float*)d_in[16];
    const float* lw0 = (const float*)d_in[17];
    const float* lb0 = (const float*)d_in[18];
    const float* lw1 = (const float*)d_in[19];
    const float* lb1 = (const float*)d_in[20];
    float* out = (float*)d_out;

    char* base = (char*)d_ws;
    u16* xfh   = (u16*)(base + 0);
    u16* xfl   = (u16*)(base + 2097152);
    u16* wcfh  = (u16*)(base + 4194304);
    u16* wcfl  = (u16*)(base + 5242880);
    u16* b2fh  = (u16*)(base + 6291456);
    u16* b2fl  = (u16*)(base + 6356992);
    u16* w3fh  = (u16*)(base + 6422528);
    u16* w3fl  = (u16*)(base + 6447104);
    float* lw0t  = (float*)(base + 6471680);
    float* lw1t  = (float*)(base + 6488064);
    u16* Ffh   = (u16*)(base + 6553600);
    u16* Ffl   = (u16*)(base + 7602176);
    float* u   = (float*)(base + 8650752);
    float* v_t = (float*)(base + 9175040);
    float* Spart = (float*)(base + 9699328);
    // total 10747904 bytes (~10.3 MB)

    hipLaunchKernelGGL(p0_prep, dim3(6400), dim3(256), 0, stream,
                       x, cw0, cw1, cw2, cw3, mw0, mw1, mw2, mw3, lw0, lw1,
                       xfh, xfl, wcfh, wcfl, b2fh, b2fl, w3fh, w3fl, lw0t, lw1t);
    hipLaunchKernelGGL(k1f_conv, dim3(128, 4), dim3(256), 0, stream,
                       xfh, xfl, wcfh, wcfl, cb0, cb1, cb2, cb3, Ffh, Ffl);
    hipLaunchKernelGGL(k2_uv, dim3(128), dim3(256), 0, stream,
                       Ffh, Ffl, b2fh, b2fl, mb0, u, v_t);
    hipLaunchKernelGGL(k3_pair, dim3(2048), dim3(128), 0, stream,
                       u, v_t, w3fh, w3fl, mb1, mb2, mb3, Spart);
    hipLaunchKernelGGL(k4_head, dim3(256), dim3(256), 0, stream,
                       Spart, lw0t, lb0, lw1t, lb1, out);
}

// Round 7
// 174.838 us; speedup vs baseline: 1.5318x; 1.0626x over previous
//
#include <hip/hip_runtime.h>
#include <hip/hip_bf16.h>

#define SLOPE 0.1f
typedef unsigned short u16;
typedef unsigned int u32;
typedef __attribute__((ext_vector_type(8))) short short8;
typedef __attribute__((ext_vector_type(4))) float floatx4;

__device__ __forceinline__ float lrelu(float x) { return x > 0.0f ? x : SLOPE * x; }

// round-nearest split: x ~= hi + lo (bf16 each), rel err ~2^-17
__device__ __forceinline__ void split_rn(float x, u16* h, u16* l) {
    union { __hip_bfloat16 b; u16 u; } c1, c2;
    c1.b = __float2bfloat16(x);
    float hf = __bfloat162float(c1.b);
    c2.b = __float2bfloat16(x - hf);
    *h = c1.u; *l = c2.u;
}

// truncation split of a PAIR of fp32 -> packed hi-u32 and lo-u32 (v_perm pack)
__device__ __forceinline__ void pack2x2(float v0, float v1, u32& h, u32& l) {
    u32 a0 = __float_as_uint(v0), a1 = __float_as_uint(v1);
    h = __builtin_amdgcn_perm(a1, a0, 0x07060302u);   // [a0.hi16 | a1.hi16]
    float r0 = v0 - __uint_as_float(a0 & 0xFFFF0000u);
    float r1 = v1 - __uint_as_float(a1 & 0xFFFF0000u);
    l = __builtin_amdgcn_perm(__float_as_uint(r1), __float_as_uint(r0), 0x07060302u);
}

__device__ __forceinline__ short8 load_frag(const u16* p) {
    union { uint4 q; short8 s; } cv;
    cv.q = *(const uint4*)p;
    return cv.s;
}

__device__ __forceinline__ floatx4 mfma16(short8 a, short8 b, floatx4 c) {
    return __builtin_amdgcn_mfma_f32_16x16x32_bf16(a, b, c, 0, 0, 0);
}

// ---------------------------------------------------------------------------
// P0: one-shot preprocessing into FRAGMENT-LINEAR layouts (unchanged).
//  seg0 xf   (1048576): x frags   [rt=128][kc=16][lane][8]
//  seg1 wcf  ( 524288): conv-w    [slot=16][nt=4][kc=16][lane][8]
//  seg2 b2f  (  32768): mw0 split [nh=2][nt=4][kc=8][lane][8]
//  seg3 w3f  (  12288): mw1..3    [layer=3][mt=4][kc=2][lane][8]
//  seg4 lw0t (   4096): fp32 transposed
//  seg5 lw1t (  16384): fp32 transposed
// ---------------------------------------------------------------------------
__global__ __launch_bounds__(256) void p0_prep(
    const float* __restrict__ x,
    const float* __restrict__ cw0, const float* __restrict__ cw1,
    const float* __restrict__ cw2, const float* __restrict__ cw3,
    const float* __restrict__ mw0, const float* __restrict__ mw1,
    const float* __restrict__ mw2, const float* __restrict__ mw3,
    const float* __restrict__ lw0, const float* __restrict__ lw1,
    u16* __restrict__ xfh, u16* __restrict__ xfl,
    u16* __restrict__ wcfh, u16* __restrict__ wcfl,
    u16* __restrict__ b2fh, u16* __restrict__ b2fl,
    u16* __restrict__ w3fh, u16* __restrict__ w3fl,
    float* __restrict__ lw0t, float* __restrict__ lw1t)
{
    int idx = blockIdx.x * 256 + threadIdx.x;
    if (idx < 1048576) {
        const int j = idx & 7, lane = (idx >> 3) & 63;
        const int kc = (idx >> 9) & 15, rt = idx >> 13;
        const int l15 = lane & 15, quad = lane >> 4;
        split_rn(x[(rt * 16 + l15) * 512 + kc * 32 + quad * 8 + j], &xfh[idx], &xfl[idx]);
        return;
    }
    idx -= 1048576;
    if (idx < 524288) {
        const int j = idx & 7, lane = (idx >> 3) & 63;
        const int kc = (idx >> 9) & 15, nt = (idx >> 13) & 3, slot = idx >> 15;
        int branch, base;
        if (slot == 0)      { branch = 0; base = 0; }
        else if (slot < 4)  { branch = 1; base = 1; }
        else if (slot < 9)  { branch = 2; base = 4; }
        else                { branch = 3; base = 9; }
        const int dk = slot - base, ksz = 2 * branch + 1;
        const float* cw = branch == 0 ? cw0 : branch == 1 ? cw1 : branch == 2 ? cw2 : cw3;
        const int c = nt * 16 + (lane & 15);
        const int e = kc * 32 + (lane >> 4) * 8 + j;
        split_rn(cw[(c * ksz + dk) * 512 + e], &wcfh[idx], &wcfl[idx]);
        return;
    }
    idx -= 524288;
    if (idx < 32768) {
        const int j = idx & 7, lane = (idx >> 3) & 63;
        const int kc = (idx >> 9) & 7, nt = (idx >> 12) & 3, nh = idx >> 14;
        const int n = nh * 64 + nt * 16 + (lane & 15);
        const int k = kc * 32 + (lane >> 4) * 8 + j;
        split_rn(mw0[(n & 63) * 512 + (n >> 6) * 256 + k], &b2fh[idx], &b2fl[idx]);
        return;
    }
    idx -= 32768;
    if (idx < 12288) {
        const int j = idx & 7, lane = (idx >> 3) & 63;
        const int kc = (idx >> 9) & 1, mt = (idx >> 10) & 3, layer = idx >> 12;
        const float* mw = layer == 0 ? mw1 : layer == 1 ? mw2 : mw3;
        const int ch = mt * 16 + (lane & 15);
        const int k = kc * 32 + (lane >> 4) * 8 + j;
        split_rn(mw[ch * 64 + k], &w3fh[idx], &w3fl[idx]);
        return;
    }
    idx -= 12288;
    if (idx < 4096) { const int k = idx >> 6, n = idx & 63; lw0t[idx] = lw0[n * 64 + k]; return; }
    idx -= 4096;
    if (idx < 16384) { const int k = idx >> 8, n = idx & 255; lw1t[idx] = lw1[n * 64 + k]; return; }
}

// ---------------------------------------------------------------------------
// K1f: fused conv GEMM (unchanged from R6): per (rt, branch) accumulate over
// all taps in AGPRs, LDS-reduce, bias+lrelu+split -> F frag-linear.
// ---------------------------------------------------------------------------
__global__ __launch_bounds__(256) void k1f_conv(
    const u16* __restrict__ xfh, const u16* __restrict__ xfl,
    const u16* __restrict__ wcfh, const u16* __restrict__ wcfl,
    const float* __restrict__ cb0, const float* __restrict__ cb1,
    const float* __restrict__ cb2, const float* __restrict__ cb3,
    u16* __restrict__ Ffh, u16* __restrict__ Ffl)
{
    __shared__ float P[4][16][72];

    const int t = threadIdx.x, lane = t & 63, w = t >> 6;
    const int rt = blockIdx.x;                 // 0..127
    const int br = blockIdx.y;                 // 0..3
    const int base = br * br;                  // 0,1,4,9
    const int ksz = 2 * br + 1;
    const int l15 = lane & 15, quad = lane >> 4;

    floatx4 acc[4];
    #pragma unroll
    for (int j = 0; j < 4; ++j) acc[j] = (floatx4)0.0f;

    const int nunits = ksz * 16;
    for (int unit = w; unit < nunits; unit += 4) {
        const int dk = unit >> 4, kc = unit & 15;
        const int rts = rt + dk - br;          // tap shift in whole 16-row tiles
        if (rts < 0 || rts >= 128) continue;
        const int aoff = ((rts * 16 + kc) * 64 + lane) * 8;
        const short8 ah = load_frag(xfh + aoff);
        const short8 al = load_frag(xfl + aoff);
        const int slot = base + dk;
        #pragma unroll
        for (int nt = 0; nt < 4; ++nt) {
            const int boff = (((slot * 4 + nt) * 16 + kc) * 64 + lane) * 8;
            const short8 bh = load_frag(wcfh + boff);
            const short8 bl = load_frag(wcfl + boff);
            acc[nt] = mfma16(ah, bh, acc[nt]);
            acc[nt] = mfma16(ah, bl, acc[nt]);
            acc[nt] = mfma16(al, bh, acc[nt]);
        }
    }

    #pragma unroll
    for (int nt = 0; nt < 4; ++nt)
        #pragma unroll
        for (int r = 0; r < 4; ++r)
            P[w][quad * 4 + r][nt * 16 + l15] = acc[nt][r];
    __syncthreads();

    const float* cb = br == 0 ? cb0 : br == 1 ? cb1 : br == 2 ? cb2 : cb3;
    const int row = t >> 4, c4 = (t & 15) * 4;
    u16 h4[4], l4[4];
    #pragma unroll
    for (int i = 0; i < 4; ++i) {
        float val = P[0][row][c4 + i] + P[1][row][c4 + i]
                  + P[2][row][c4 + i] + P[3][row][c4 + i] + cb[c4 + i];
        split_rn(lrelu(val), &h4[i], &l4[i]);
    }
    const int m4 = br * 64 + c4;
    const int dst = ((rt * 8 + (m4 >> 5)) * 64 + ((m4 >> 3) & 3) * 16 + row) * 8 + (m4 & 7);
    *(ushort4*)(Ffh + dst) = make_ushort4(h4[0], h4[1], h4[2], h4[3]);
    *(ushort4*)(Ffl + dst) = make_ushort4(l4[0], l4[1], l4[2], l4[3]);
}

// ---------------------------------------------------------------------------
// K2: [u|v] = F @ B2^T.  grid (128 rt, 2 nh); 4 waves, each 2 kc; LDS reduce.
// u gets +mb0; v written transposed (b-major) as v_t.
// ---------------------------------------------------------------------------
__global__ __launch_bounds__(256) void k2_uv(
    const u16* __restrict__ Ffh, const u16* __restrict__ Ffl,
    const u16* __restrict__ b2fh, const u16* __restrict__ b2fl,
    const float* __restrict__ mb0,
    float* __restrict__ u, float* __restrict__ v_t)
{
    __shared__ float P[4][16][72];

    const int t = threadIdx.x, lane = t & 63, w = t >> 6;
    const int rt = blockIdx.x;
    const int nh = blockIdx.y;
    const int l15 = lane & 15, quad = lane >> 4;

    floatx4 acc[4];
    #pragma unroll
    for (int j = 0; j < 4; ++j) acc[j] = (floatx4)0.0f;

    #pragma unroll
    for (int kk = 0; kk < 2; ++kk) {
        const int kc = w * 2 + kk;
        const int aoff = ((rt * 8 + kc) * 64 + lane) * 8;
        const short8 ah = load_frag(Ffh + aoff);
        const short8 al = load_frag(Ffl + aoff);
        #pragma unroll
        for (int nt = 0; nt < 4; ++nt) {
            const int boff = (((nh * 4 + nt) * 8 + kc) * 64 + lane) * 8;
            const short8 bh = load_frag(b2fh + boff);
            const short8 bl = load_frag(b2fl + boff);
            acc[nt] = mfma16(ah, bh, acc[nt]);
            acc[nt] = mfma16(ah, bl, acc[nt]);
            acc[nt] = mfma16(al, bh, acc[nt]);
        }
    }

    #pragma unroll
    for (int nt = 0; nt < 4; ++nt)
        #pragma unroll
        for (int r = 0; r < 4; ++r)
            P[w][quad * 4 + r][nt * 16 + l15] = acc[nt][r];
    __syncthreads();

    const int row = t >> 4, c4 = (t & 15) * 4;
    const int rglob = rt * 16 + row;
    float4 oo;
    #pragma unroll
    for (int i = 0; i < 4; ++i)
        (&oo.x)[i] = P[0][row][c4 + i] + P[1][row][c4 + i]
                   + P[2][row][c4 + i] + P[3][row][c4 + i];
    if (nh == 0) {
        oo.x += mb0[c4 + 0]; oo.y += mb0[c4 + 1];
        oo.z += mb0[c4 + 2]; oo.w += mb0[c4 + 3];
        *(float4*)(u + rglob * 64 + c4) = oo;
    } else {
        const int i = rglob >> 4, b = rglob & 15;
        *(float4*)(v_t + (b * 128 + i) * 64 + c4) = oo;
    }
}

// ---------------------------------------------------------------------------
// K3: per jb, 4 waves x 32 i's; H bf16 hi/lo in LDS, rows wave-private (zero
// inter-layer barriers).  Coalesced v_t loads, frag-linear weights, v_perm
// packed epilogue.  Layer-3 reduced over own 32 i in regs (shfl) -> Spart
// quarter per wave.  grid: 2048 blocks, 256 thr; LDS 36.9 KB -> 4 blocks/CU
// -> 16 waves/CU (4/SIMD).
// ---------------------------------------------------------------------------
__global__ __launch_bounds__(256, 4) void k3_pair(
    const float* __restrict__ u, const float* __restrict__ v_t,
    const u16* __restrict__ w3fh, const u16* __restrict__ w3fl,
    const float* __restrict__ mb1, const float* __restrict__ mb2,
    const float* __restrict__ mb3,
    float* __restrict__ Spart)
{
    __shared__ __align__(16) u16 Hh[128][72];
    __shared__ __align__(16) u16 Hl[128][72];
    __shared__ __align__(16) float us[64];

    const int t = threadIdx.x, lane = t & 63, w = t >> 6;   // w in {0..3}
    const int jb = blockIdx.x, b = jb & 15;
    const int l15 = lane & 15, quad = lane >> 4;
    const int i0 = w * 32;                       // wave's 32-i strip

    if (t < 64) us[t] = u[jb * 64 + t];
    __syncthreads();

    // H1 build: contiguous 8 KB stream per wave from v_t
    const float* vb = v_t + (b * 128 + i0) * 64;
    #pragma unroll
    for (int n = 0; n < 8; ++n) {
        const int idx = n * 64 + lane;
        const int il = idx >> 4, c4 = (idx & 15) * 4;
        const float4 vv = *(const float4*)(vb + idx * 4);
        const float4 uu = *(const float4*)(&us[c4]);
        const float a0 = lrelu(vv.x + uu.x), a1 = lrelu(vv.y + uu.y);
        const float a2 = lrelu(vv.z + uu.z), a3 = lrelu(vv.w + uu.w);
        u32 h01, l01, h23, l23;
        pack2x2(a0, a1, h01, l01);
        pack2x2(a2, a3, h23, l23);
        *(uint2*)&Hh[i0 + il][c4] = make_uint2(h01, h23);
        *(uint2*)&Hl[i0 + il][c4] = make_uint2(l01, l23);
    }

    const float* mbp[3] = {mb1, mb2, mb3};
    for (int layer = 0; layer < 3; ++layer) {
        floatx4 acc[4][2];                       // [mt=ch][nt=i]
        #pragma unroll
        for (int i = 0; i < 4; ++i)
            #pragma unroll
            for (int j = 0; j < 2; ++j) acc[i][j] = (floatx4)0.0f;

        #pragma unroll
        for (int kc = 0; kc < 2; ++kc) {
            short8 ah[4], al[4];
            #pragma unroll
            for (int mt = 0; mt < 4; ++mt) {
                const int aoff = (((layer * 4 + mt) * 2 + kc) * 64 + lane) * 8;
                ah[mt] = load_frag(w3fh + aoff);
                al[mt] = load_frag(w3fl + aoff);
            }
            const int k0 = kc * 32 + quad * 8;
            #pragma unroll
            for (int nt = 0; nt < 2; ++nt) {
                const short8 bh = load_frag(&Hh[i0 + nt * 16 + l15][k0]);
                const short8 bl = load_frag(&Hl[i0 + nt * 16 + l15][k0]);
                #pragma unroll
                for (int mt = 0; mt < 4; ++mt) {
                    acc[mt][nt] = mfma16(ah[mt], bh, acc[mt][nt]);
                    acc[mt][nt] = mfma16(ah[mt], bl, acc[mt][nt]);
                    acc[mt][nt] = mfma16(al[mt], bh, acc[mt][nt]);
                }
            }
        }

        if (layer < 2) {
            #pragma unroll
            for (int mt = 0; mt < 4; ++mt) {
                float bias[4];
                #pragma unroll
                for (int r = 0; r < 4; ++r) bias[r] = mbp[layer][mt * 16 + quad * 4 + r];
                #pragma unroll
                for (int nt = 0; nt < 2; ++nt) {
                    const int i = i0 + nt * 16 + l15;
                    const float v0 = lrelu(acc[mt][nt][0] + bias[0]);
                    const float v1 = lrelu(acc[mt][nt][1] + bias[1]);
                    const float v2 = lrelu(acc[mt][nt][2] + bias[2]);
                    const float v3 = lrelu(acc[mt][nt][3] + bias[3]);
                    u32 h01, l01, h23, l23;
                    pack2x2(v0, v1, h01, l01);
                    pack2x2(v2, v3, h23, l23);
                    *(uint2*)&Hh[i][mt * 16 + quad * 4] = make_uint2(h01, h23);
                    *(uint2*)&Hl[i][mt * 16 + quad * 4] = make_uint2(l01, l23);
                }
            }
        } else {
            // final layer: lrelu + reduce over this wave's 32 i
            #pragma unroll
            for (int mt = 0; mt < 4; ++mt) {
                float bias[4];
                #pragma unroll
                for (int r = 0; r < 4; ++r) bias[r] = mbp[2][mt * 16 + quad * 4 + r];
                float4 sv;
                #pragma unroll
                for (int r = 0; r < 4; ++r) {
                    float val = lrelu(acc[mt][0][r] + bias[r])
                              + lrelu(acc[mt][1][r] + bias[r]);
                    val += __shfl_xor(val, 1, 16);
                    val += __shfl_xor(val, 2, 16);
                    val += __shfl_xor(val, 4, 16);
                    val += __shfl_xor(val, 8, 16);
                    (&sv.x)[r] = val;
                }
                if (l15 == 0)
                    *(float4*)(Spart + jb * 256 + w * 64 + mt * 16 + quad * 4) = sv;
            }
        }
    }
}

// ---------------------------------------------------------------------------
// K4: head over 8 jb per block; S = 4 Spart quarters summed;
// T1 = lrelu(S@lw0.T+lb0); out = lrelu(T1@lw1.T+lb1).  grid: 256 x 256 thr.
// ---------------------------------------------------------------------------
__global__ __launch_bounds__(256) void k4_head(
    const float* __restrict__ Spart,
    const float* __restrict__ lw0t, const float* __restrict__ lb0,
    const float* __restrict__ lw1t, const float* __restrict__ lb1,
    float* __restrict__ out)
{
    __shared__ float Ss[8][64];
    __shared__ float T1[8][64];

    const int t = threadIdx.x;
    const int jb0 = blockIdx.x * 8;

    #pragma unroll
    for (int p = 0; p < 2; ++p) {
        const int idx = t + 256 * p;
        const int jbb = idx >> 6, ch = idx & 63;
        const float* sp = Spart + (jb0 + jbb) * 256 + ch;
        Ss[jbb][ch] = sp[0] + sp[64] + sp[128] + sp[192];
    }
    __syncthreads();

    #pragma unroll
    for (int p = 0; p < 2; ++p) {
        const int idx = t + 256 * p;
        const int jbb = idx >> 6, c = idx & 63;
        float a = lb0[c];
        #pragma unroll 8
        for (int k = 0; k < 64; ++k) a += Ss[jbb][k] * lw0t[k * 64 + c];
        T1[jbb][c] = lrelu(a);
    }
    __syncthreads();

    const int c = t;
    float acc[8];
    const float base = lb1[c];
    #pragma unroll
    for (int jbb = 0; jbb < 8; ++jbb) acc[jbb] = base;
    #pragma unroll 4
    for (int k = 0; k < 64; ++k) {
        const float wv = lw1t[k * 256 + c];
        #pragma unroll
        for (int jbb = 0; jbb < 8; ++jbb) acc[jbb] += T1[jbb][k] * wv;
    }
    #pragma unroll
    for (int jbb = 0; jbb < 8; ++jbb)
        out[(jb0 + jbb) * 256 + c] = lrelu(acc[jbb]);
}

// ---------------------------------------------------------------------------
extern "C" void kernel_launch(void* const* d_in, const int* in_sizes, int n_in,
                              void* d_out, int out_size, void* d_ws, size_t ws_size,
                              hipStream_t stream)
{
    const float* x   = (const float*)d_in[0];
    const float* cw0 = (const float*)d_in[1];
    const float* cb0 = (const float*)d_in[2];
    const float* cw1 = (const float*)d_in[3];
    const float* cb1 = (const float*)d_in[4];
    const float* cw2 = (const float*)d_in[5];
    const float* cb2 = (const float*)d_in[6];
    const float* cw3 = (const float*)d_in[7];
    const float* cb3 = (const float*)d_in[8];
    const float* mw0 = (const float*)d_in[9];
    const float* mb0 = (const float*)d_in[10];
    const float* mw1 = (const float*)d_in[11];
    const float* mb1 = (const float*)d_in[12];
    const float* mw2 = (const float*)d_in[13];
    const float* mb2 = (const float*)d_in[14];
    const float* mw3 = (const float*)d_in[15];
    const float* mb3 = (const float*)d_in[16];
    const float* lw0 = (const float*)d_in[17];
    const float* lb0 = (const float*)d_in[18];
    const float* lw1 = (const float*)d_in[19];
    const float* lb1 = (const float*)d_in[20];
    float* out = (float*)d_out;

    char* base = (char*)d_ws;
    u16* xfh   = (u16*)(base + 0);
    u16* xfl   = (u16*)(base + 2097152);
    u16* wcfh  = (u16*)(base + 4194304);
    u16* wcfl  = (u16*)(base + 5242880);
    u16* b2fh  = (u16*)(base + 6291456);
    u16* b2fl  = (u16*)(base + 6356992);
    u16* w3fh  = (u16*)(base + 6422528);
    u16* w3fl  = (u16*)(base + 6447104);
    float* lw0t  = (float*)(base + 6471680);
    float* lw1t  = (float*)(base + 6488064);
    u16* Ffh   = (u16*)(base + 6553600);
    u16* Ffl   = (u16*)(base + 7602176);
    float* u   = (float*)(base + 8650752);
    float* v_t = (float*)(base + 9175040);
    float* Spart = (float*)(base + 9699328);   // 2048*256*4 = 2 MB
    // total 11796480 bytes (~11.3 MB)

    hipLaunchKernelGGL(p0_prep, dim3(6400), dim3(256), 0, stream,
                       x, cw0, cw1, cw2, cw3, mw0, mw1, mw2, mw3, lw0, lw1,
                       xfh, xfl, wcfh, wcfl, b2fh, b2fl, w3fh, w3fl, lw0t, lw1t);
    hipLaunchKernelGGL(k1f_conv, dim3(128, 4), dim3(256), 0, stream,
                       xfh, xfl, wcfh, wcfl, cb0, cb1, cb2, cb3, Ffh, Ffl);
    hipLaunchKernelGGL(k2_uv, dim3(128, 2), dim3(256), 0, stream,
                       Ffh, Ffl, b2fh, b2fl, mb0, u, v_t);
    hipLaunchKernelGGL(k3_pair, dim3(2048), dim3(256), 0, stream,
                       u, v_t, w3fh, w3fl, mb1, mb2, mb3, Spart);
    hipLaunchKernelGGL(k4_head, dim3(256), dim3(256), 0, stream,
                       Spart, lw0t, lb0, lw1t, lb1, out);
}

// Round 8
// 156.817 us; speedup vs baseline: 1.7079x; 1.1149x over previous
//
#include <hip/hip_runtime.h>
#include <hip/hip_bf16.h>

#define SLOPE 0.1f
typedef unsigned short u16;
typedef unsigned int u32;
typedef __attribute__((ext_vector_type(8))) short short8;
typedef __attribute__((ext_vector_type(4))) float floatx4;

__device__ __forceinline__ float lrelu(float x) { return x > 0.0f ? x : SLOPE * x; }

// round-nearest split: x ~= hi + lo (bf16 each), rel err ~2^-17
__device__ __forceinline__ void split_rn(float x, u16* h, u16* l) {
    union { __hip_bfloat16 b; u16 u; } c1, c2;
    c1.b = __float2bfloat16(x);
    float hf = __bfloat162float(c1.b);
    c2.b = __float2bfloat16(x - hf);
    *h = c1.u; *l = c2.u;
}

// truncation split of a PAIR of fp32 -> packed hi-u32 and lo-u32 (v_perm pack)
__device__ __forceinline__ void pack2x2(float v0, float v1, u32& h, u32& l) {
    u32 a0 = __float_as_uint(v0), a1 = __float_as_uint(v1);
    h = __builtin_amdgcn_perm(a1, a0, 0x07060302u);   // [a0.hi16 | a1.hi16]
    float r0 = v0 - __uint_as_float(a0 & 0xFFFF0000u);
    float r1 = v1 - __uint_as_float(a1 & 0xFFFF0000u);
    l = __builtin_amdgcn_perm(__float_as_uint(r1), __float_as_uint(r0), 0x07060302u);
}

__device__ __forceinline__ short8 load_frag(const u16* p) {
    union { uint4 q; short8 s; } cv;
    cv.q = *(const uint4*)p;
    return cv.s;
}

__device__ __forceinline__ floatx4 mfma16(short8 a, short8 b, floatx4 c) {
    return __builtin_amdgcn_mfma_f32_16x16x32_bf16(a, b, c, 0, 0, 0);
}

// ---------------------------------------------------------------------------
// P0: one-shot preprocessing into FRAGMENT-LINEAR layouts, x4 vectorized
// (4 consecutive elements per thread; inner index is contiguous in every seg).
//  seg0 xf   (1048576): x frags   [rt=128][kc=16][lane][8]
//  seg1 wcf  ( 524288): conv-w    [slot=16][nt=4][kc=16][lane][8]
//  seg2 b2f  (  32768): mw0 split [nh=2][nt=4][kc=8][lane][8]
//  seg3 w3f  (  12288): mw1..3    [layer=3][mt=4][kc=2][lane][8]
//  seg4 lw0t (   4096): fp32 transposed
//  seg5 lw1t (  16384): fp32 transposed
// total = 1638400 items = 409600 threads = 1600 blocks.
// ---------------------------------------------------------------------------
__global__ __launch_bounds__(256) void p0_prep(
    const float* __restrict__ x,
    const float* __restrict__ cw0, const float* __restrict__ cw1,
    const float* __restrict__ cw2, const float* __restrict__ cw3,
    const float* __restrict__ mw0, const float* __restrict__ mw1,
    const float* __restrict__ mw2, const float* __restrict__ mw3,
    const float* __restrict__ lw0, const float* __restrict__ lw1,
    u16* __restrict__ xfh, u16* __restrict__ xfl,
    u16* __restrict__ wcfh, u16* __restrict__ wcfl,
    u16* __restrict__ b2fh, u16* __restrict__ b2fl,
    u16* __restrict__ w3fh, u16* __restrict__ w3fl,
    float* __restrict__ lw0t, float* __restrict__ lw1t)
{
    int idx = (blockIdx.x * 256 + threadIdx.x) * 4;
    if (idx < 1048576) {
        const int j = idx & 7, lane = (idx >> 3) & 63;
        const int kc = (idx >> 9) & 15, rt = idx >> 13;
        const int l15 = lane & 15, quad = lane >> 4;
        const float4 s = *(const float4*)(x + (rt * 16 + l15) * 512 + kc * 32 + quad * 8 + j);
        u16 h[4], l[4];
        split_rn(s.x, &h[0], &l[0]); split_rn(s.y, &h[1], &l[1]);
        split_rn(s.z, &h[2], &l[2]); split_rn(s.w, &h[3], &l[3]);
        *(ushort4*)(xfh + idx) = make_ushort4(h[0], h[1], h[2], h[3]);
        *(ushort4*)(xfl + idx) = make_ushort4(l[0], l[1], l[2], l[3]);
        return;
    }
    idx -= 1048576;
    if (idx < 524288) {
        const int j = idx & 7, lane = (idx >> 3) & 63;
        const int kc = (idx >> 9) & 15, nt = (idx >> 13) & 3, slot = idx >> 15;
        int branch, base;
        if (slot == 0)      { branch = 0; base = 0; }
        else if (slot < 4)  { branch = 1; base = 1; }
        else if (slot < 9)  { branch = 2; base = 4; }
        else                { branch = 3; base = 9; }
        const int dk = slot - base, ksz = 2 * branch + 1;
        const float* cw = branch == 0 ? cw0 : branch == 1 ? cw1 : branch == 2 ? cw2 : cw3;
        const int c = nt * 16 + (lane & 15);
        const int e = kc * 32 + (lane >> 4) * 8 + j;
        const float4 s = *(const float4*)(cw + (c * ksz + dk) * 512 + e);
        u16 h[4], l[4];
        split_rn(s.x, &h[0], &l[0]); split_rn(s.y, &h[1], &l[1]);
        split_rn(s.z, &h[2], &l[2]); split_rn(s.w, &h[3], &l[3]);
        *(ushort4*)(wcfh + idx) = make_ushort4(h[0], h[1], h[2], h[3]);
        *(ushort4*)(wcfl + idx) = make_ushort4(l[0], l[1], l[2], l[3]);
        return;
    }
    idx -= 524288;
    if (idx < 32768) {
        const int j = idx & 7, lane = (idx >> 3) & 63;
        const int kc = (idx >> 9) & 7, nt = (idx >> 12) & 3, nh = idx >> 14;
        const int n = nh * 64 + nt * 16 + (lane & 15);
        const int k = kc * 32 + (lane >> 4) * 8 + j;
        const float4 s = *(const float4*)(mw0 + (n & 63) * 512 + (n >> 6) * 256 + k);
        u16 h[4], l[4];
        split_rn(s.x, &h[0], &l[0]); split_rn(s.y, &h[1], &l[1]);
        split_rn(s.z, &h[2], &l[2]); split_rn(s.w, &h[3], &l[3]);
        *(ushort4*)(b2fh + idx) = make_ushort4(h[0], h[1], h[2], h[3]);
        *(ushort4*)(b2fl + idx) = make_ushort4(l[0], l[1], l[2], l[3]);
        return;
    }
    idx -= 32768;
    if (idx < 12288) {
        const int j = idx & 7, lane = (idx >> 3) & 63;
        const int kc = (idx >> 9) & 1, mt = (idx >> 10) & 3, layer = idx >> 12;
        const float* mw = layer == 0 ? mw1 : layer == 1 ? mw2 : mw3;
        const int ch = mt * 16 + (lane & 15);
        const int k = kc * 32 + (lane >> 4) * 8 + j;
        const float4 s = *(const float4*)(mw + ch * 64 + k);
        u16 h[4], l[4];
        split_rn(s.x, &h[0], &l[0]); split_rn(s.y, &h[1], &l[1]);
        split_rn(s.z, &h[2], &l[2]); split_rn(s.w, &h[3], &l[3]);
        *(ushort4*)(w3fh + idx) = make_ushort4(h[0], h[1], h[2], h[3]);
        *(ushort4*)(w3fl + idx) = make_ushort4(l[0], l[1], l[2], l[3]);
        return;
    }
    idx -= 12288;
    if (idx < 4096) {
        const int k = idx >> 6, n = idx & 63;
        float4 o;
        o.x = lw0[(n + 0) * 64 + k]; o.y = lw0[(n + 1) * 64 + k];
        o.z = lw0[(n + 2) * 64 + k]; o.w = lw0[(n + 3) * 64 + k];
        *(float4*)(lw0t + idx) = o;
        return;
    }
    idx -= 4096;
    if (idx < 16384) {
        const int k = idx >> 8, n = idx & 255;
        float4 o;
        o.x = lw1[(n + 0) * 64 + k]; o.y = lw1[(n + 1) * 64 + k];
        o.z = lw1[(n + 2) * 64 + k]; o.w = lw1[(n + 3) * 64 + k];
        *(float4*)(lw1t + idx) = o;
        return;
    }
}

// ---------------------------------------------------------------------------
// K1f: fused conv GEMM, 2-rt tiling: block = (rt-pair, branch), 512 thr =
// 8 waves, K-split 8-way over (dk,kc) units.  B (weight) frags loaded once
// per unit and reused for both rt -> weight L2 traffic halved vs R7.
// Two-phase LDS reduce + bias/lrelu/split epilogue -> F frag-linear.
// grid: (64, 4).
// ---------------------------------------------------------------------------
__global__ __launch_bounds__(512) void k1f_conv(
    const u16* __restrict__ xfh, const u16* __restrict__ xfl,
    const u16* __restrict__ wcfh, const u16* __restrict__ wcfl,
    const float* __restrict__ cb0, const float* __restrict__ cb1,
    const float* __restrict__ cb2, const float* __restrict__ cb3,
    u16* __restrict__ Ffh, u16* __restrict__ Ffl)
{
    __shared__ float P[8][16][72];   // 36.9 KB

    const int t = threadIdx.x, lane = t & 63, w = t >> 6;   // 8 waves
    const int rtp = blockIdx.x;                // 0..63 -> rt, rt+64
    const int br = blockIdx.y;                 // 0..3
    const int base = br * br;                  // 0,1,4,9
    const int ksz = 2 * br + 1;
    const int l15 = lane & 15, quad = lane >> 4;

    floatx4 acc[2][4];
    #pragma unroll
    for (int r = 0; r < 2; ++r)
        #pragma unroll
        for (int j = 0; j < 4; ++j) acc[r][j] = (floatx4)0.0f;

    const int nunits = ksz * 16;
    for (int unit = w; unit < nunits; unit += 8) {
        const int dk = unit >> 4, kc = unit & 15;
        const int slot = base + dk;
        short8 bh[4], bl[4];
        #pragma unroll
        for (int nt = 0; nt < 4; ++nt) {
            const int boff = (((slot * 4 + nt) * 16 + kc) * 64 + lane) * 8;
            bh[nt] = load_frag(wcfh + boff);
            bl[nt] = load_frag(wcfl + boff);
        }
        #pragma unroll
        for (int r = 0; r < 2; ++r) {
            const int rts = rtp + r * 64 + dk - br;
            if (rts < 0 || rts >= 128) continue;
            const int aoff = ((rts * 16 + kc) * 64 + lane) * 8;
            const short8 ah = load_frag(xfh + aoff);
            const short8 al = load_frag(xfl + aoff);
            #pragma unroll
            for (int nt = 0; nt < 4; ++nt) {
                acc[r][nt] = mfma16(ah, bh[nt], acc[r][nt]);
                acc[r][nt] = mfma16(ah, bl[nt], acc[r][nt]);
                acc[r][nt] = mfma16(al, bh[nt], acc[r][nt]);
            }
        }
    }

    const float* cb = br == 0 ? cb0 : br == 1 ? cb1 : br == 2 ? cb2 : cb3;
    #pragma unroll
    for (int r = 0; r < 2; ++r) {
        #pragma unroll
        for (int nt = 0; nt < 4; ++nt)
            #pragma unroll
            for (int rr = 0; rr < 4; ++rr)
                P[w][quad * 4 + rr][nt * 16 + l15] = acc[r][nt][rr];
        __syncthreads();
        if (t < 256) {
            const int row = t >> 4, c4 = (t & 15) * 4;
            u16 h4[4], l4[4];
            #pragma unroll
            for (int i = 0; i < 4; ++i) {
                float val = cb[c4 + i];
                #pragma unroll
                for (int ww = 0; ww < 8; ++ww) val += P[ww][row][c4 + i];
                split_rn(lrelu(val), &h4[i], &l4[i]);
            }
            const int rt = rtp + r * 64;
            const int m4 = br * 64 + c4;
            const int dst = ((rt * 8 + (m4 >> 5)) * 64 + ((m4 >> 3) & 3) * 16 + row) * 8 + (m4 & 7);
            *(ushort4*)(Ffh + dst) = make_ushort4(h4[0], h4[1], h4[2], h4[3]);
            *(ushort4*)(Ffl + dst) = make_ushort4(l4[0], l4[1], l4[2], l4[3]);
        }
        __syncthreads();
    }
}

// ---------------------------------------------------------------------------
// K2: [u|v] = F @ B2^T.  grid (128 rt, 2 nh); 4 waves, each 2 kc; LDS reduce.
// u gets +mb0; v written transposed (b-major) as v_t.  (unchanged from R7)
// ---------------------------------------------------------------------------
__global__ __launch_bounds__(256) void k2_uv(
    const u16* __restrict__ Ffh, const u16* __restrict__ Ffl,
    const u16* __restrict__ b2fh, const u16* __restrict__ b2fl,
    const float* __restrict__ mb0,
    float* __restrict__ u, float* __restrict__ v_t)
{
    __shared__ float P[4][16][72];

    const int t = threadIdx.x, lane = t & 63, w = t >> 6;
    const int rt = blockIdx.x;
    const int nh = blockIdx.y;
    const int l15 = lane & 15, quad = lane >> 4;

    floatx4 acc[4];
    #pragma unroll
    for (int j = 0; j < 4; ++j) acc[j] = (floatx4)0.0f;

    #pragma unroll
    for (int kk = 0; kk < 2; ++kk) {
        const int kc = w * 2 + kk;
        const int aoff = ((rt * 8 + kc) * 64 + lane) * 8;
        const short8 ah = load_frag(Ffh + aoff);
        const short8 al = load_frag(Ffl + aoff);
        #pragma unroll
        for (int nt = 0; nt < 4; ++nt) {
            const int boff = (((nh * 4 + nt) * 8 + kc) * 64 + lane) * 8;
            const short8 bh = load_frag(b2fh + boff);
            const short8 bl = load_frag(b2fl + boff);
            acc[nt] = mfma16(ah, bh, acc[nt]);
            acc[nt] = mfma16(ah, bl, acc[nt]);
            acc[nt] = mfma16(al, bh, acc[nt]);
        }
    }

    #pragma unroll
    for (int nt = 0; nt < 4; ++nt)
        #pragma unroll
        for (int r = 0; r < 4; ++r)
            P[w][quad * 4 + r][nt * 16 + l15] = acc[nt][r];
    __syncthreads();

    const int row = t >> 4, c4 = (t & 15) * 4;
    const int rglob = rt * 16 + row;
    float4 oo;
    #pragma unroll
    for (int i = 0; i < 4; ++i)
        (&oo.x)[i] = P[0][row][c4 + i] + P[1][row][c4 + i]
                   + P[2][row][c4 + i] + P[3][row][c4 + i];
    if (nh == 0) {
        oo.x += mb0[c4 + 0]; oo.y += mb0[c4 + 1];
        oo.z += mb0[c4 + 2]; oo.w += mb0[c4 + 3];
        *(float4*)(u + rglob * 64 + c4) = oo;
    } else {
        const int i = rglob >> 4, b = rglob & 15;
        *(float4*)(v_t + (b * 128 + i) * 64 + c4) = oo;
    }
}

// ---------------------------------------------------------------------------
// K3: per jb, 4 waves x 32 i's; H bf16 hi/lo in LDS, rows wave-private.
// Now FULLY barrier-free: u row read as one loop-invariant float4 per lane
// (c4 = (lane&15)*4 is constant across the H1-build loop).  Layer-3 reduced
// over own 32 i in regs (shfl) -> Spart quarter per wave.
// grid: 2048 blocks, 256 thr; LDS 36.9 KB -> 4 blocks/CU -> 16 waves/CU.
// ---------------------------------------------------------------------------
__global__ __launch_bounds__(256, 4) void k3_pair(
    const float* __restrict__ u, const float* __restrict__ v_t,
    const u16* __restrict__ w3fh, const u16* __restrict__ w3fl,
    const float* __restrict__ mb1, const float* __restrict__ mb2,
    const float* __restrict__ mb3,
    float* __restrict__ Spart)
{
    __shared__ __align__(16) u16 Hh[128][72];
    __shared__ __align__(16) u16 Hl[128][72];

    const int t = threadIdx.x, lane = t & 63, w = t >> 6;   // w in {0..3}
    const int jb = blockIdx.x, b = jb & 15;
    const int l15 = lane & 15, quad = lane >> 4;
    const int i0 = w * 32;                       // wave's 32-i strip
    const int c4 = l15 * 4;

    // u row: loop-invariant per lane (one global float4, L1/L2-hot)
    const float4 uu = *(const float4*)(u + jb * 64 + c4);

    // H1 build: contiguous 8 KB stream per wave from v_t
    const float* vb = v_t + (b * 128 + i0) * 64;
    #pragma unroll
    for (int n = 0; n < 8; ++n) {
        const int idx = n * 64 + lane;
        const int il = idx >> 4;                  // c4 == (idx&15)*4 == l15*4
        const float4 vv = *(const float4*)(vb + idx * 4);
        const float a0 = lrelu(vv.x + uu.x), a1 = lrelu(vv.y + uu.y);
        const float a2 = lrelu(vv.z + uu.z), a3 = lrelu(vv.w + uu.w);
        u32 h01, l01, h23, l23;
        pack2x2(a0, a1, h01, l01);
        pack2x2(a2, a3, h23, l23);
        *(uint2*)&Hh[i0 + il][c4] = make_uint2(h01, h23);
        *(uint2*)&Hl[i0 + il][c4] = make_uint2(l01, l23);
    }

    const float* mbp[3] = {mb1, mb2, mb3};
    for (int layer = 0; layer < 3; ++layer) {
        floatx4 acc[4][2];                       // [mt=ch][nt=i]
        #pragma unroll
        for (int i = 0; i < 4; ++i)
            #pragma unroll
            for (int j = 0; j < 2; ++j) acc[i][j] = (floatx4)0.0f;

        #pragma unroll
        for (int kc = 0; kc < 2; ++kc) {
            short8 ah[4], al[4];
            #pragma unroll
            for (int mt = 0; mt < 4; ++mt) {
                const int aoff = (((layer * 4 + mt) * 2 + kc) * 64 + lane) * 8;
                ah[mt] = load_frag(w3fh + aoff);
                al[mt] = load_frag(w3fl + aoff);
            }
            const int k0 = kc * 32 + quad * 8;
            #pragma unroll
            for (int nt = 0; nt < 2; ++nt) {
                const short8 bh = load_frag(&Hh[i0 + nt * 16 + l15][k0]);
                const short8 bl = load_frag(&Hl[i0 + nt * 16 + l15][k0]);
                #pragma unroll
                for (int mt = 0; mt < 4; ++mt) {
                    acc[mt][nt] = mfma16(ah[mt], bh, acc[mt][nt]);
                    acc[mt][nt] = mfma16(ah[mt], bl, acc[mt][nt]);
                    acc[mt][nt] = mfma16(al[mt], bh, acc[mt][nt]);
                }
            }
        }

        if (layer < 2) {
            #pragma unroll
            for (int mt = 0; mt < 4; ++mt) {
                float bias[4];
                #pragma unroll
                for (int r = 0; r < 4; ++r) bias[r] = mbp[layer][mt * 16 + quad * 4 + r];
                #pragma unroll
                for (int nt = 0; nt < 2; ++nt) {
                    const int i = i0 + nt * 16 + l15;
                    const float v0 = lrelu(acc[mt][nt][0] + bias[0]);
                    const float v1 = lrelu(acc[mt][nt][1] + bias[1]);
                    const float v2 = lrelu(acc[mt][nt][2] + bias[2]);
                    const float v3 = lrelu(acc[mt][nt][3] + bias[3]);
                    u32 h01, l01, h23, l23;
                    pack2x2(v0, v1, h01, l01);
                    pack2x2(v2, v3, h23, l23);
                    *(uint2*)&Hh[i][mt * 16 + quad * 4] = make_uint2(h01, h23);
                    *(uint2*)&Hl[i][mt * 16 + quad * 4] = make_uint2(l01, l23);
                }
            }
        } else {
            // final layer: lrelu + reduce over this wave's 32 i
            #pragma unroll
            for (int mt = 0; mt < 4; ++mt) {
                float bias[4];
                #pragma unroll
                for (int r = 0; r < 4; ++r) bias[r] = mbp[2][mt * 16 + quad * 4 + r];
                float4 sv;
                #pragma unroll
                for (int r = 0; r < 4; ++r) {
                    float val = lrelu(acc[mt][0][r] + bias[r])
                              + lrelu(acc[mt][1][r] + bias[r]);
                    val += __shfl_xor(val, 1, 16);
                    val += __shfl_xor(val, 2, 16);
                    val += __shfl_xor(val, 4, 16);
                    val += __shfl_xor(val, 8, 16);
                    (&sv.x)[r] = val;
                }
                if (l15 == 0)
                    *(float4*)(Spart + jb * 256 + w * 64 + mt * 16 + quad * 4) = sv;
            }
        }
    }
}

// ---------------------------------------------------------------------------
// K4: head over 8 jb per block; S = 4 Spart quarters summed;
// T1 = lrelu(S@lw0.T+lb0); out = lrelu(T1@lw1.T+lb1).  grid: 256 x 256 thr.
// ---------------------------------------------------------------------------
__global__ __launch_bounds__(256) void k4_head(
    const float* __restrict__ Spart,
    const float* __restrict__ lw0t, const float* __restrict__ lb0,
    const float* __restrict__ lw1t, const float* __restrict__ lb1,
    float* __restrict__ out)
{
    __shared__ float Ss[8][64];
    __shared__ float T1[8][64];

    const int t = threadIdx.x;
    const int jb0 = blockIdx.x * 8;

    #pragma unroll
    for (int p = 0; p < 2; ++p) {
        const int idx = t + 256 * p;
        const int jbb = idx >> 6, ch = idx & 63;
        const float* sp = Spart + (jb0 + jbb) * 256 + ch;
        Ss[jbb][ch] = sp[0] + sp[64] + sp[128] + sp[192];
    }
    __syncthreads();

    #pragma unroll
    for (int p = 0; p < 2; ++p) {
        const int idx = t + 256 * p;
        const int jbb = idx >> 6, c = idx & 63;
        float a = lb0[c];
        #pragma unroll 8
        for (int k = 0; k < 64; ++k) a += Ss[jbb][k] * lw0t[k * 64 + c];
        T1[jbb][c] = lrelu(a);
    }
    __syncthreads();

    const int c = t;
    float acc[8];
    const float base = lb1[c];
    #pragma unroll
    for (int jbb = 0; jbb < 8; ++jbb) acc[jbb] = base;
    #pragma unroll 4
    for (int k = 0; k < 64; ++k) {
        const float wv = lw1t[k * 256 + c];
        #pragma unroll
        for (int jbb = 0; jbb < 8; ++jbb) acc[jbb] += T1[jbb][k] * wv;
    }
    #pragma unroll
    for (int jbb = 0; jbb < 8; ++jbb)
        out[(jb0 + jbb) * 256 + c] = lrelu(acc[jbb]);
}

// ---------------------------------------------------------------------------
extern "C" void kernel_launch(void* const* d_in, const int* in_sizes, int n_in,
                              void* d_out, int out_size, void* d_ws, size_t ws_size,
                              hipStream_t stream)
{
    const float* x   = (const float*)d_in[0];
    const float* cw0 = (const float*)d_in[1];
    const float* cb0 = (const float*)d_in[2];
    const float* cw1 = (const float*)d_in[3];
    const float* cb1 = (const float*)d_in[4];
    const float* cw2 = (const float*)d_in[5];
    const float* cb2 = (const float*)d_in[6];
    const float* cw3 = (const float*)d_in[7];
    const float* cb3 = (const float*)d_in[8];
    const float* mw0 = (const float*)d_in[9];
    const float* mb0 = (const float*)d_in[10];
    const float* mw1 = (const float*)d_in[11];
    const float* mb1 = (const float*)d_in[12];
    const float* mw2 = (const float*)d_in[13];
    const float* mb2 = (const float*)d_in[14];
    const float* mw3 = (const float*)d_in[15];
    const float* mb3 = (const float*)d_in[16];
    const float* lw0 = (const float*)d_in[17];
    const float* lb0 = (const float*)d_in[18];
    const float* lw1 = (const float*)d_in[19];
    const float* lb1 = (const float*)d_in[20];
    float* out = (float*)d_out;

    char* base = (char*)d_ws;
    u16* xfh   = (u16*)(base + 0);
    u16* xfl   = (u16*)(base + 2097152);
    u16* wcfh  = (u16*)(base + 4194304);
    u16* wcfl  = (u16*)(base + 5242880);
    u16* b2fh  = (u16*)(base + 6291456);
    u16* b2fl  = (u16*)(base + 6356992);
    u16* w3fh  = (u16*)(base + 6422528);
    u16* w3fl  = (u16*)(base + 6447104);
    float* lw0t  = (float*)(base + 6471680);
    float* lw1t  = (float*)(base + 6488064);
    u16* Ffh   = (u16*)(base + 6553600);
    u16* Ffl   = (u16*)(base + 7602176);
    float* u   = (float*)(base + 8650752);
    float* v_t = (float*)(base + 9175040);
    float* Spart = (float*)(base + 9699328);   // 2048*256*4 = 2 MB
    // total 11796480 bytes (~11.3 MB)

    hipLaunchKernelGGL(p0_prep, dim3(1600), dim3(256), 0, stream,
                       x, cw0, cw1, cw2, cw3, mw0, mw1, mw2, mw3, lw0, lw1,
                       xfh, xfl, wcfh, wcfl, b2fh, b2fl, w3fh, w3fl, lw0t, lw1t);
    hipLaunchKernelGGL(k1f_conv, dim3(64, 4), dim3(512), 0, stream,
                       xfh, xfl, wcfh, wcfl, cb0, cb1, cb2, cb3, Ffh, Ffl);
    hipLaunchKernelGGL(k2_uv, dim3(128, 2), dim3(256), 0, stream,
                       Ffh, Ffl, b2fh, b2fl, mb0, u, v_t);
    hipLaunchKernelGGL(k3_pair, dim3(2048), dim3(256), 0, stream,
                       u, v_t, w3fh, w3fl, mb1, mb2, mb3, Spart);
    hipLaunchKernelGGL(k4_head, dim3(256), dim3(256), 0, stream,
                       Spart, lw0t, lb0, lw1t, lb1, out);
}